// Round 6
// baseline (295.840 us; speedup 1.0000x reference)
//
#include <hip/hip_runtime.h>
#include <hip/hip_bf16.h>

#define B_ 64
#define T_ 128
#define E_ 256
#define H_ 256
#define OW_ 512   // output row width = 2*H (elements)
#define LP 264    // LDS bf16 row pitch for proj_mfma staging (elements)
#define MAGIC 0x5AD00000u

typedef unsigned short ushort_t;
typedef __attribute__((ext_vector_type(8))) short bf16x8;   // 8 bf16 = 4 VGPRs
typedef __attribute__((ext_vector_type(4))) float f32x4;    // 4 f32 acc

// Workgroup barrier WITHOUT the compiler's vmcnt(0) drain (validated r7/r8).
#define LGKM_BARRIER() asm volatile("s_waitcnt lgkmcnt(0)\n\ts_barrier" ::: "memory")
// Keep weight fragments loop-carried (r12: -6%, kept).
#define PIN_FRAG(x) asm volatile("" : "+v"(x))

__device__ __forceinline__ ushort_t f2bf(float f) {
    unsigned int x = __float_as_uint(f);
    unsigned int r = x + 0x7FFFu + ((x >> 16) & 1u);
    return (ushort_t)(r >> 16);
}
__device__ __forceinline__ float fast_tanh(float x) {
    float e = __expf(2.0f * x);
    return 1.0f - 2.0f * __builtin_amdgcn_rcpf(e + 1.0f);
}
__device__ __forceinline__ bf16x8 load_bfrag(const float* W, const float* M,
                                             size_t base) {
    float4 a = *(const float4*)(W + base);
    float4 b = *(const float4*)(W + base + 4);
    if (M) {
        float4 ma = *(const float4*)(M + base);
        float4 mb = *(const float4*)(M + base + 4);
        a.x *= ma.x; a.y *= ma.y; a.z *= ma.z; a.w *= ma.w;
        b.x *= mb.x; b.y *= mb.y; b.z *= mb.z; b.w *= mb.w;
    }
    union { bf16x8 v; ushort_t u[8]; } r;
    r.u[0] = f2bf(a.x); r.u[1] = f2bf(a.y); r.u[2] = f2bf(a.z); r.u[3] = f2bf(a.w);
    r.u[4] = f2bf(b.x); r.u[5] = f2bf(b.y); r.u[6] = f2bf(b.z); r.u[7] = f2bf(b.w);
    return r.v;
}

// Fragment-major LDS A-layout (r9-verified): element (r,k) at
//   off = (k>>5)*512 + ((k>>3)&3)*128 + r*8 + (k&7)
// Reader lane L reads frag kk as ds_read_b128 at element L*8 + kk*512
// (= A-row l15, k = kk*32 + quad*8 + j): exact MFMA A-frag, linear in lane.
// Pad-row lanes ((l15&2)!=0; their C rows discarded) read broadcast addr 0.
__device__ __forceinline__ int a_off(int r, int k) {
    return ((k >> 5) << 9) + (((k >> 3) & 3) << 7) + (r << 3) + (k & 7);
}

// Stage 4 consecutive f32 (k = lane*4, k%4==0 -> same 8-group, 8B-aligned)
// into a frag-major tile row `slot` as one 8-byte LDS write.
__device__ __forceinline__ void stage_row(ushort_t* tile, int slot, int lane,
                                          float4 v) {
    union { unsigned long long q; ushort_t u[4]; } p;
    p.u[0] = f2bf(v.x); p.u[1] = f2bf(v.y); p.u[2] = f2bf(v.z); p.u[3] = f2bf(v.w);
    *(unsigned long long*)(tile + a_off(slot, lane * 4)) = p.q;
}

// ---------------------------------------------------------------------------
// r14: proj_mfma ELIMINATED (it was the constant ~112 us in front of the
// scan every round). Both input projections fold into the scan dispatch:
//  producer (WG 0..7):  per step stages 8 emb rows (t+1 prefetch) into a
//    2nd frag-major LDS tile and computes xp0 = emb@Wi0^T on the fly
//    (16 extra MFMA, independent of the h-chain -> ILP), plus rec0.
//    Publishes h0 via agent-scope stores to `out` + 8-step flag protocol.
//    xf workspace GONE (h0 itself is the published payload).
//  consumer (WG 8..15): holds Wr1'+Wi1; per step stages h0(t+1) from `out`
//    (flag-gated, 1-ahead prefetch, L3 hits) and computes
//    xp1 = h0@Wi1^T + b1 itself (bit-identical to the old xf values),
//    plus rec1.
// Both roles: 128 VGPRs of weights + 2 frag sets + accs ~ 240 regs,
// 2 waves/SIMD at launch_bounds(512,1).
// Layout invariants (r8-r13 verified): batch i at A-slot (i>>1)*4+(i&1);
// C rows quad*4+reg (reg<2): lane(quad,l15) owns batches {quad*2,quad*2+1}
// x cols {wv*32+tc*16+l15}.
// ---------------------------------------------------------------------------
__device__ __forceinline__ void producer_core(
    int grp, ushort_t (*hb)[4096], ushort_t (*eb)[4096],
    const int* __restrict__ tokens, const float* __restrict__ emb,
    const float* Wr0, const float* m0, const float* Wi0,
    const float* b0v, const float* tau0,
    float* out, unsigned int* flag)
{
    const int tid  = threadIdx.x;
    const int lane = tid & 63;
    const int wv   = tid >> 6;     // 0..7
    const int quad = lane >> 4;
    const int l15  = lane & 15;
    const int n0   = wv * 32;
    const int bg   = grp * 8;
    const int slot = (wv >> 1) * 4 + (wv & 1);   // A-slot for batch bg+wv

    bf16x8 Br[2][8], Bi[2][8];
    float  b0r[2], inv_tau[2], h_prev[2][2];
    #pragma unroll
    for (int tc = 0; tc < 2; ++tc) {
        const int c = n0 + tc * 16 + l15;
        b0r[tc] = b0v[c];
        inv_tau[tc] = 1.0f / (logf(1.0f + __expf(tau0[c])) + 0.1f);
        h_prev[tc][0] = h_prev[tc][1] = 0.f;
        #pragma unroll
        for (int kk = 0; kk < 8; ++kk) {
            Br[tc][kk] = load_bfrag(Wr0, m0, (size_t)c * H_ + kk * 32 + quad * 8);
            Bi[tc][kk] = load_bfrag(Wi0, nullptr, (size_t)c * E_ + kk * 32 + quad * 8);
        }
    }

    int woff[2][2];
    #pragma unroll
    for (int tc = 0; tc < 2; ++tc)
        #pragma unroll
        for (int reg = 0; reg < 2; ++reg)
            woff[tc][reg] = a_off(quad * 4 + reg, n0 + tc * 16 + l15);
    const int ab = ((l15 & 2) == 0) ? (lane * 8) : 0;

    for (int i = tid; i < 4096; i += 512)
        ((unsigned int*)&hb[0][0])[i] = 0u;   // h0(-1) = 0 (both buffers)
    {   // stage emb tile for t=0
        const int tk = tokens[(bg + wv) * T_ + 0];
        float4 v = *(const float4*)(emb + (size_t)tk * E_ + lane * 4);
        stage_row(eb[0], slot, lane, v);
    }
    __syncthreads();

    for (int t = 0; t < T_; ++t) {
        const int rb = t & 1;

        #pragma unroll
        for (int tc = 0; tc < 2; ++tc)
            #pragma unroll
            for (int kk = 0; kk < 8; ++kk) { PIN_FRAG(Br[tc][kk]); PIN_FRAG(Bi[tc][kk]); }

        bf16x8 Af[8], Ef[8];
        {
            const ushort_t* a0 = &hb[rb][0];
            const ushort_t* e0 = &eb[rb][0];
            #pragma unroll
            for (int kk = 0; kk < 8; ++kk) {
                Af[kk] = *(const bf16x8*)(a0 + ab + kk * 512);
                Ef[kk] = *(const bf16x8*)(e0 + ab + kk * 512);
            }
        }

        // issue emb(t+1) gather early (consumed post-MFMA)
        float4 ev;
        const bool have_next = (t + 1 < T_);
        if (have_next) {
            const int tk = tokens[(bg + wv) * T_ + t + 1];
            ev = *(const float4*)(emb + (size_t)tk * E_ + lane * 4);
        }

        f32x4 acc0[2] = {{0.f,0.f,0.f,0.f},{0.f,0.f,0.f,0.f}};
        f32x4 accp[2];
        #pragma unroll
        for (int tc = 0; tc < 2; ++tc)
            accp[tc] = (f32x4){b0r[tc], b0r[tc], b0r[tc], b0r[tc]};
        #pragma unroll
        for (int kk = 0; kk < 8; ++kk)
            #pragma unroll
            for (int tc = 0; tc < 2; ++tc) {
                acc0[tc] = __builtin_amdgcn_mfma_f32_16x16x32_bf16(
                    Af[kk], Br[tc][kk], acc0[tc], 0, 0, 0);
                accp[tc] = __builtin_amdgcn_mfma_f32_16x16x32_bf16(
                    Ef[kk], Bi[tc][kk], accp[tc], 0, 0, 0);
            }

        if (have_next) stage_row(eb[rb ^ 1], slot, lane, ev);

        #pragma unroll
        for (int tc = 0; tc < 2; ++tc) {
            const int c = n0 + tc * 16 + l15;
            #pragma unroll
            for (int reg = 0; reg < 2; ++reg) {
                const int b = bg + quad * 2 + reg;
                const float pre = accp[tc][reg] + acc0[tc][reg];
                const float hn  = h_prev[tc][reg]
                                + (fast_tanh(pre) - h_prev[tc][reg]) * inv_tau[tc];
                h_prev[tc][reg] = hn;
                hb[rb ^ 1][woff[tc][reg]] = f2bf(hn);
                // agent-scope: cross-XCD visible once retired (r8 mechanism)
                __hip_atomic_store(&out[(size_t)(b * T_ + t) * OW_ + c], hn,
                                   __ATOMIC_RELAXED, __HIP_MEMORY_SCOPE_AGENT);
            }
        }

        if ((t & 7) == 7) {
            __syncthreads();   // drains vmcnt -> h0 rows <= t retired
            if (tid == 0)
                __hip_atomic_store(flag, MAGIC + (unsigned)((t + 1) >> 3),
                                   __ATOMIC_RELEASE, __HIP_MEMORY_SCOPE_AGENT);
        } else {
            LGKM_BARRIER();
        }
    }
}

__device__ __forceinline__ void consumer_core(
    int grp, ushort_t (*hb)[4096], ushort_t (*eb)[4096],
    const float* Wr1, const float* m1, const float* Wi1,
    const float* b1v, const float* tau1,
    float* out, unsigned int* flag)
{
    const int tid  = threadIdx.x;
    const int lane = tid & 63;
    const int wv   = tid >> 6;
    const int quad = lane >> 4;
    const int l15  = lane & 15;
    const int n0   = wv * 32;
    const int bg   = grp * 8;
    const int slot = (wv >> 1) * 4 + (wv & 1);

    bf16x8 Br[2][8], Bi[2][8];
    float  b1r[2], inv_tau[2], h_prev[2][2];
    #pragma unroll
    for (int tc = 0; tc < 2; ++tc) {
        const int c = n0 + tc * 16 + l15;
        b1r[tc] = b1v[c];
        inv_tau[tc] = 1.0f / (logf(1.0f + __expf(tau1[c])) + 0.1f);
        h_prev[tc][0] = h_prev[tc][1] = 0.f;
        #pragma unroll
        for (int kk = 0; kk < 8; ++kk) {
            Br[tc][kk] = load_bfrag(Wr1, m1, (size_t)c * H_ + kk * 32 + quad * 8);
            Bi[tc][kk] = load_bfrag(Wi1, nullptr, (size_t)c * H_ + kk * 32 + quad * 8);
        }
    }

    int woff[2][2];
    #pragma unroll
    for (int tc = 0; tc < 2; ++tc)
        #pragma unroll
        for (int reg = 0; reg < 2; ++reg)
            woff[tc][reg] = a_off(quad * 4 + reg, n0 + tc * 16 + l15);
    const int ab = ((l15 & 2) == 0) ? (lane * 8) : 0;

    for (int i = tid; i < 4096; i += 512)
        ((unsigned int*)&hb[0][0])[i] = 0u;   // h1(-1) = 0

    // prologue: wait chunk 1 (h0 rows 0..7), stage h0(0)
    if (tid == 0) {
        for (;;) {
            unsigned d = __hip_atomic_load(flag, __ATOMIC_ACQUIRE,
                                           __HIP_MEMORY_SCOPE_AGENT) - MAGIC;
            if (d >= 1u && d <= 16u) break;
            __builtin_amdgcn_s_sleep(2);
        }
    }
    __syncthreads();
    {
        float4 v = *(const float4*)(out + (size_t)((bg + wv) * T_ + 0) * OW_
                                    + lane * 4);
        stage_row(eb[0], slot, lane, v);
    }
    __syncthreads();

    for (int t = 0; t < T_; ++t) {
        const int rb = t & 1;

        #pragma unroll
        for (int tc = 0; tc < 2; ++tc)
            #pragma unroll
            for (int kk = 0; kk < 8; ++kk) { PIN_FRAG(Br[tc][kk]); PIN_FRAG(Bi[tc][kk]); }

        bf16x8 Af[8], Ef[8];
        {
            const ushort_t* a0 = &hb[rb][0];
            const ushort_t* e0 = &eb[rb][0];
            #pragma unroll
            for (int kk = 0; kk < 8; ++kk) {
                Af[kk] = *(const bf16x8*)(a0 + ab + kk * 512);
                Ef[kk] = *(const bf16x8*)(e0 + ab + kk * 512);
            }
        }

        // early prefetch of h0(t+1) when flag-covered (within chunk)
        const bool have_next = (t + 1 < T_);
        const bool edge = ((t & 7) == 7);
        float4 hv;
        if (have_next && !edge)
            hv = *(const float4*)(out + (size_t)((bg + wv) * T_ + t + 1) * OW_
                                  + lane * 4);

        f32x4 acc1[2] = {{0.f,0.f,0.f,0.f},{0.f,0.f,0.f,0.f}};
        f32x4 acc2[2];
        #pragma unroll
        for (int tc = 0; tc < 2; ++tc)
            acc2[tc] = (f32x4){b1r[tc], b1r[tc], b1r[tc], b1r[tc]};
        #pragma unroll
        for (int kk = 0; kk < 8; ++kk)
            #pragma unroll
            for (int tc = 0; tc < 2; ++tc) {
                acc1[tc] = __builtin_amdgcn_mfma_f32_16x16x32_bf16(
                    Af[kk], Br[tc][kk], acc1[tc], 0, 0, 0);
                acc2[tc] = __builtin_amdgcn_mfma_f32_16x16x32_bf16(
                    Ef[kk], Bi[tc][kk], acc2[tc], 0, 0, 0);
            }

        #pragma unroll
        for (int tc = 0; tc < 2; ++tc) {
            const int c = n0 + tc * 16 + l15;
            #pragma unroll
            for (int reg = 0; reg < 2; ++reg) {
                const int b = bg + quad * 2 + reg;
                const float pre = acc2[tc][reg] + acc1[tc][reg];
                const float hn  = h_prev[tc][reg]
                                + (fast_tanh(pre) - h_prev[tc][reg]) * inv_tau[tc];
                h_prev[tc][reg] = hn;
                hb[rb ^ 1][woff[tc][reg]] = f2bf(hn);
                out[(size_t)(b * T_ + t) * OW_ + H_ + c] = hn;   // h1 plain store
            }
        }

        if (have_next) {
            if (edge) {   // next chunk: wait flag, then (covered) load h0(t+1)
                if (tid == 0) {
                    const unsigned need = (unsigned)((t + 1) >> 3) + 1u;
                    for (;;) {
                        unsigned d = __hip_atomic_load(flag, __ATOMIC_ACQUIRE,
                                                       __HIP_MEMORY_SCOPE_AGENT) - MAGIC;
                        if (d >= need && d <= 16u) break;
                        __builtin_amdgcn_s_sleep(2);
                    }
                }
                __syncthreads();
                hv = *(const float4*)(out + (size_t)((bg + wv) * T_ + t + 1) * OW_
                                      + lane * 4);
            }
            stage_row(eb[rb ^ 1], slot, lane, hv);
            LGKM_BARRIER();
        }
    }
}

__global__ __launch_bounds__(512, 1)
void ltc_fused(const int* __restrict__ tokens, const float* __restrict__ emb,
               const float* __restrict__ Wi0, const float* __restrict__ b0v,
               const float* __restrict__ Wr0, const float* __restrict__ m0,
               const float* __restrict__ t0,
               const float* __restrict__ Wi1, const float* __restrict__ b1v,
               const float* __restrict__ Wr1, const float* __restrict__ m1,
               const float* __restrict__ t1,
               float* out, unsigned int* flags)
{
    __shared__ __align__(16) ushort_t hb[2][4096];
    __shared__ __align__(16) ushort_t eb[2][4096];
    if (blockIdx.x < 8)
        producer_core(blockIdx.x, hb, eb, tokens, emb,
                      Wr0, m0, Wi0, b0v, t0, out, flags + blockIdx.x);
    else
        consumer_core(blockIdx.x - 8, hb, eb,
                      Wr1, m1, Wi1, b1v, t1, out, flags + blockIdx.x - 8);
}

// ---------------------------------------------------------------------------
// Fallback path (ws too small for flags): r13-proven standalone scan + proj.
// ---------------------------------------------------------------------------
__global__ __launch_bounds__(512, 1)
void ltc_single(const float* xp, int xp_stride, int xp_col,
                float* hout, int out_col,
                const float* __restrict__ Wr, const float* __restrict__ mk,
                const float* __restrict__ tu)
{
    __shared__ __align__(16) ushort_t hb[2][4096];
    const int tid  = threadIdx.x;
    const int lane = tid & 63;
    const int wv   = tid >> 6;
    const int quad = lane >> 4;
    const int l15  = lane & 15;
    const int n0   = wv * 32;
    const int bg   = blockIdx.x * 8;

    bf16x8 Bf[2][8];
    #pragma unroll
    for (int tc = 0; tc < 2; ++tc)
        #pragma unroll
        for (int kk = 0; kk < 8; ++kk)
            Bf[tc][kk] = load_bfrag(Wr, mk,
                (size_t)(n0 + tc * 16 + l15) * H_ + kk * 32 + quad * 8);

    float inv_tau[2], h_prev[2][2], xp_c[2][2], xp_n[2][2], xp_nn[2][2];
    #pragma unroll
    for (int tc = 0; tc < 2; ++tc) {
        inv_tau[tc] = 1.0f / (logf(1.0f + __expf(tu[n0 + tc * 16 + l15])) + 0.1f);
        #pragma unroll
        for (int reg = 0; reg < 2; ++reg) {
            h_prev[tc][reg] = 0.f; xp_c[tc][reg] = xp_n[tc][reg] = xp_nn[tc][reg] = 0.f;
            const int b = bg + quad * 2 + reg;
            const int c = n0 + tc * 16 + l15;
            xp_c[tc][reg] = xp[(size_t)(b * T_ + 0) * xp_stride + xp_col + c];
            xp_n[tc][reg] = xp[(size_t)(b * T_ + 1) * xp_stride + xp_col + c];
        }
    }
    int woff[2][2];
    #pragma unroll
    for (int tc = 0; tc < 2; ++tc)
        #pragma unroll
        for (int reg = 0; reg < 2; ++reg)
            woff[tc][reg] = a_off(quad * 4 + reg, n0 + tc * 16 + l15);
    const int ab = ((l15 & 2) == 0) ? (lane * 8) : 0;

    for (int i = tid; i < 4096; i += 512)
        ((unsigned int*)&hb[0][0])[i] = 0u;
    __syncthreads();

    for (int t = 0; t < T_; ++t) {
        const int rb = t & 1;
        bf16x8 Af[8];
        {
            const ushort_t* a0 = &hb[rb][0];
            #pragma unroll
            for (int kk = 0; kk < 8; ++kk)
                Af[kk] = *(const bf16x8*)(a0 + ab + kk * 512);
        }
        if (t + 2 < T_) {
            #pragma unroll
            for (int tc = 0; tc < 2; ++tc)
                #pragma unroll
                for (int reg = 0; reg < 2; ++reg) {
                    const int b = bg + quad * 2 + reg;
                    xp_nn[tc][reg] = xp[(size_t)(b * T_ + t + 2) * xp_stride
                                        + xp_col + n0 + tc * 16 + l15];
                }
        }
        f32x4 acc[2] = {{0.f,0.f,0.f,0.f},{0.f,0.f,0.f,0.f}};
        #pragma unroll
        for (int kk = 0; kk < 8; ++kk)
            #pragma unroll
            for (int tc = 0; tc < 2; ++tc)
                acc[tc] = __builtin_amdgcn_mfma_f32_16x16x32_bf16(
                    Af[kk], Bf[tc][kk], acc[tc], 0, 0, 0);
        #pragma unroll
        for (int tc = 0; tc < 2; ++tc) {
            const int c = n0 + tc * 16 + l15;
            #pragma unroll
            for (int reg = 0; reg < 2; ++reg) {
                const int b = bg + quad * 2 + reg;
                const float pre = xp_c[tc][reg] + acc[tc][reg];
                const float hn  = h_prev[tc][reg]
                                + (fast_tanh(pre) - h_prev[tc][reg]) * inv_tau[tc];
                h_prev[tc][reg] = hn;
                hb[rb ^ 1][woff[tc][reg]] = f2bf(hn);
                hout[(size_t)(b * T_ + t) * OW_ + out_col + c] = hn;
            }
        }
        #pragma unroll
        for (int tc = 0; tc < 2; ++tc)
            #pragma unroll
            for (int reg = 0; reg < 2; ++reg) {
                xp_c[tc][reg] = xp_n[tc][reg];
                xp_n[tc][reg] = xp_nn[tc][reg];
            }
        if (t + 1 < T_) LGKM_BARRIER();
    }
}

__global__ __launch_bounds__(512, 2)
void proj_mfma(const float* __restrict__ src, int src_stride, int src_col,
               const int* __restrict__ tok,
               const float* __restrict__ Wi,
               const float* __restrict__ bias,
               float* __restrict__ dst, int dst_stride, int dst_col)
{
    const int tid  = threadIdx.x;
    const int lane = tid & 63;
    const int wv   = tid >> 6;
    const int quad = lane >> 4;
    const int l15  = lane & 15;
    const int n0   = wv * 32;

    __shared__ __align__(16) ushort_t As[32][LP];

    bf16x8 Bf[2][8];
    float  bj[2];
    #pragma unroll
    for (int tc = 0; tc < 2; ++tc) {
        const int n = n0 + tc * 16 + l15;
        bj[tc] = bias[n];
        #pragma unroll
        for (int kk = 0; kk < 8; ++kk)
            Bf[tc][kk] = load_bfrag(Wi, nullptr, (size_t)n * H_ + kk * 32 + quad * 8);
    }

    const int r0 = blockIdx.x * 32;
    {
        const int row = tid >> 4;
        const int seg = tid & 15;
        const size_t sb = (tok ? (size_t)tok[r0 + row] : (size_t)(r0 + row))
                          * src_stride + src_col + seg * 16;
        union { uint4 q[2]; ushort_t u[16]; } p;
        #pragma unroll
        for (int h = 0; h < 2; ++h) {
            float4 f0 = *(const float4*)(src + sb + h * 8);
            float4 f1 = *(const float4*)(src + sb + h * 8 + 4);
            p.u[h*8+0] = f2bf(f0.x); p.u[h*8+1] = f2bf(f0.y);
            p.u[h*8+2] = f2bf(f0.z); p.u[h*8+3] = f2bf(f0.w);
            p.u[h*8+4] = f2bf(f1.x); p.u[h*8+5] = f2bf(f1.y);
            p.u[h*8+6] = f2bf(f1.z); p.u[h*8+7] = f2bf(f1.w);
        }
        *(uint4*)&As[row][seg * 16]     = p.q[0];
        *(uint4*)&As[row][seg * 16 + 8] = p.q[1];
    }
    __syncthreads();

    #pragma unroll
    for (int rt = 0; rt < 2; ++rt) {
        bf16x8 Af[8];
        #pragma unroll
        for (int kk = 0; kk < 8; ++kk)
            Af[kk] = *(const bf16x8*)&As[rt * 16 + l15][kk * 32 + quad * 8];

        f32x4 acc[2] = {{bj[0],bj[0],bj[0],bj[0]}, {bj[1],bj[1],bj[1],bj[1]}};
        #pragma unroll
        for (int kk = 0; kk < 8; ++kk)
            #pragma unroll
            for (int tc = 0; tc < 2; ++tc)
                acc[tc] = __builtin_amdgcn_mfma_f32_16x16x32_bf16(
                    Af[kk], Bf[tc][kk], acc[tc], 0, 0, 0);

        #pragma unroll
        for (int tc = 0; tc < 2; ++tc) {
            const int c = n0 + tc * 16 + l15;
            #pragma unroll
            for (int reg = 0; reg < 4; ++reg) {
                const int r = r0 + rt * 16 + quad * 4 + reg;
                dst[(size_t)r * dst_stride + dst_col + c] = acc[tc][reg];
            }
        }
    }
}

extern "C" void kernel_launch(void* const* d_in, const int* in_sizes, int n_in,
                              void* d_out, int out_size, void* d_ws, size_t ws_size,
                              hipStream_t stream)
{
    const int*   tokens = (const int*)d_in[0];
    const float* emb    = (const float*)d_in[1];
    const float* W_in0  = (const float*)d_in[2];
    const float* W_rec0 = (const float*)d_in[3];
    const float* b0     = (const float*)d_in[4];
    const float* tau0   = (const float*)d_in[5];
    const float* mask0  = (const float*)d_in[6];
    const float* W_in1  = (const float*)d_in[7];
    const float* W_rec1 = (const float*)d_in[8];
    const float* b1     = (const float*)d_in[9];
    const float* tau1   = (const float*)d_in[10];
    const float* mask1  = (const float*)d_in[11];
    float* out = (float*)d_out;    // [8192, 512] f32
    (void)in_sizes; (void)n_in; (void)out_size;

    if (ws_size >= 64) {
        // flags arrive poisoned (0xAA..) each launch; consumers' window check
        // treats poison as not-ready; producers overwrite with MAGIC+c.
        unsigned int* flags = (unsigned int*)d_ws;
        ltc_fused<<<dim3(16), dim3(512), 0, stream>>>(
            tokens, emb, W_in0, b0, W_rec0, mask0, tau0,
            W_in1, b1, W_rec1, mask1, tau1, out, flags);
    } else {
        proj_mfma<<<dim3(256), dim3(512), 0, stream>>>(
            emb, E_, 0, tokens, W_in0, b0, out, OW_, H_);
        ltc_single<<<dim3(8), dim3(512), 0, stream>>>(
            out, OW_, H_, out, 0, W_rec0, mask0, tau0);
        proj_mfma<<<dim3(256), dim3(512), 0, stream>>>(
            out, OW_, 0, nullptr, W_in1, b1, out, OW_, H_);
        ltc_single<<<dim3(8), dim3(512), 0, stream>>>(
            out, OW_, H_, out, H_, W_rec1, mask1, tau1);
    }
}

// Round 7
// 292.582 us; speedup vs baseline: 1.0111x; 1.0111x over previous
//
#include <hip/hip_runtime.h>
#include <hip/hip_bf16.h>

#define B_ 64
#define T_ 128
#define E_ 256
#define H_ 256
#define OW_ 512   // output row width = 2*H (elements)
#define LP 264    // LDS bf16 row pitch for row-major staging tiles (elements)
#define MAGIC 0x5AD00000u

typedef unsigned short ushort_t;
typedef __attribute__((ext_vector_type(8))) short bf16x8;   // 8 bf16 = 4 VGPRs
typedef __attribute__((ext_vector_type(4))) float f32x4;    // 4 f32 acc

// Workgroup barrier WITHOUT the compiler's vmcnt(0) drain (validated r7/r8).
#define LGKM_BARRIER() asm volatile("s_waitcnt lgkmcnt(0)\n\ts_barrier" ::: "memory")
// Keep weight fragments loop-carried (r12: -6%, kept).
#define PIN_FRAG(x) asm volatile("" : "+v"(x))

__device__ __forceinline__ ushort_t f2bf(float f) {
    unsigned int x = __float_as_uint(f);
    unsigned int r = x + 0x7FFFu + ((x >> 16) & 1u);
    return (ushort_t)(r >> 16);
}
__device__ __forceinline__ float fast_tanh(float x) {
    float e = __expf(2.0f * x);
    return 1.0f - 2.0f * __builtin_amdgcn_rcpf(e + 1.0f);
}
__device__ __forceinline__ bf16x8 load_bfrag(const float* W, const float* M,
                                             size_t base) {
    float4 a = *(const float4*)(W + base);
    float4 b = *(const float4*)(W + base + 4);
    if (M) {
        float4 ma = *(const float4*)(M + base);
        float4 mb = *(const float4*)(M + base + 4);
        a.x *= ma.x; a.y *= ma.y; a.z *= ma.z; a.w *= ma.w;
        b.x *= mb.x; b.y *= mb.y; b.z *= mb.z; b.w *= mb.w;
    }
    union { bf16x8 v; ushort_t u[8]; } r;
    r.u[0] = f2bf(a.x); r.u[1] = f2bf(a.y); r.u[2] = f2bf(a.z); r.u[3] = f2bf(a.w);
    r.u[4] = f2bf(b.x); r.u[5] = f2bf(b.y); r.u[6] = f2bf(b.z); r.u[7] = f2bf(b.w);
    return r.v;
}

// Fragment-major LDS A-layout for hb (r9-verified): element (r,k) at
//   off = (k>>5)*512 + ((k>>3)&3)*128 + r*8 + (k&7)
// Reader lane L reads frag kk as b128 at element L*8 + kk*512 (linear).
// NOTE (r14 post-mortem): a frag-major ROW occupies banks 4r..4r+3 ONLY, so
// staging a whole row from one wave is a 32-way write conflict. hb is safe
// (its epilogue writes scatter across columns); staged tiles must NOT use it.
__device__ __forceinline__ int a_off(int r, int k) {
    return ((k >> 5) << 9) + (((k >> 3) & 3) << 7) + (r << 3) + (k & 7);
}

// Row-major staging write (r15 fix): 8B at [slot][lane*4] -> bank
// (4*slot + 2*lane) % 32 = ~4-way (vs 32-way in the frag-major tile).
__device__ __forceinline__ void stage_row_rm(ushort_t (*tile)[LP], int slot,
                                             int lane, float4 v) {
    union { unsigned long long q; ushort_t u[4]; } p;
    p.u[0] = f2bf(v.x); p.u[1] = f2bf(v.y); p.u[2] = f2bf(v.z); p.u[3] = f2bf(v.w);
    *(unsigned long long*)(&tile[slot][lane * 4]) = p.q;
}

// ---------------------------------------------------------------------------
// r15 = r14 (proj folded into the scan; proj_mfma dispatch eliminated, its
// ~47us + launch gone) with the staging tile moved to the r8-proven
// ROW-MAJOR [16][LP] layout. r14's frag-major staging was a measured 32-way
// write bank conflict (SQ_LDS_BANK_CONFLICT 526K -> 1.38M, ~415 cy/step/WG).
//  producer (WG 0..7): stages emb rows (t+1 prefetch) row-major, computes
//    xp0 = emb@Wi0^T + rec0 per step; publishes h0 (agent-scope stores to
//    out) + 8-step flag protocol.
//  consumer (WG 8..15): stages h0(t+1) from out (flag-gated), computes
//    xp1 = h0@Wi1^T + b1 + rec1.
// Layout invariants (r8-r14 verified): batch i at A-slot (i>>1)*4+(i&1);
// C rows quad*4+reg (reg<2): lane(quad,l15) owns batches {quad*2,quad*2+1}
// x cols {wv*32+tc*16+l15}. hb frag-major w/ broadcast-pad reads.
// ---------------------------------------------------------------------------
__device__ __forceinline__ void producer_core(
    int grp, ushort_t (*hb)[4096], ushort_t (*eb)[16][LP],
    const int* __restrict__ tokens, const float* __restrict__ emb,
    const float* Wr0, const float* m0, const float* Wi0,
    const float* b0v, const float* tau0,
    float* out, unsigned int* flag)
{
    const int tid  = threadIdx.x;
    const int lane = tid & 63;
    const int wv   = tid >> 6;     // 0..7
    const int quad = lane >> 4;
    const int l15  = lane & 15;
    const int n0   = wv * 32;
    const int bg   = grp * 8;
    const int slot = (wv >> 1) * 4 + (wv & 1);   // A-slot for batch bg+wv

    bf16x8 Br[2][8], Bi[2][8];
    float  b0r[2], inv_tau[2], h_prev[2][2];
    #pragma unroll
    for (int tc = 0; tc < 2; ++tc) {
        const int c = n0 + tc * 16 + l15;
        b0r[tc] = b0v[c];
        inv_tau[tc] = 1.0f / (logf(1.0f + __expf(tau0[c])) + 0.1f);
        h_prev[tc][0] = h_prev[tc][1] = 0.f;
        #pragma unroll
        for (int kk = 0; kk < 8; ++kk) {
            Br[tc][kk] = load_bfrag(Wr0, m0, (size_t)c * H_ + kk * 32 + quad * 8);
            Bi[tc][kk] = load_bfrag(Wi0, nullptr, (size_t)c * E_ + kk * 32 + quad * 8);
        }
    }

    int woff[2][2];
    #pragma unroll
    for (int tc = 0; tc < 2; ++tc)
        #pragma unroll
        for (int reg = 0; reg < 2; ++reg)
            woff[tc][reg] = a_off(quad * 4 + reg, n0 + tc * 16 + l15);
    const int ab    = ((l15 & 2) == 0) ? (lane * 8) : 0;            // hb read
    const int ebase = ((l15 & 2) == 0) ? (l15 * LP + quad * 8) : 0; // eb read

    for (int i = tid; i < 4096; i += 512)
        ((unsigned int*)&hb[0][0])[i] = 0u;   // h0(-1) = 0 (both buffers)
    {   // stage emb tile for t=0
        const int tk = tokens[(bg + wv) * T_ + 0];
        float4 v = *(const float4*)(emb + (size_t)tk * E_ + lane * 4);
        stage_row_rm(eb[0], slot, lane, v);
    }
    __syncthreads();

    for (int t = 0; t < T_; ++t) {
        const int rb = t & 1;

        #pragma unroll
        for (int tc = 0; tc < 2; ++tc)
            #pragma unroll
            for (int kk = 0; kk < 8; ++kk) { PIN_FRAG(Br[tc][kk]); PIN_FRAG(Bi[tc][kk]); }

        bf16x8 Af[8], Ef[8];
        {
            const ushort_t* a0 = &hb[rb][0];
            const ushort_t* e0 = &eb[rb][0][0];
            #pragma unroll
            for (int kk = 0; kk < 8; ++kk) {
                Af[kk] = *(const bf16x8*)(a0 + ab + kk * 512);
                Ef[kk] = *(const bf16x8*)(e0 + ebase + kk * 32);
            }
        }

        // issue emb(t+1) gather early (consumed post-MFMA)
        float4 ev;
        const bool have_next = (t + 1 < T_);
        if (have_next) {
            const int tk = tokens[(bg + wv) * T_ + t + 1];
            ev = *(const float4*)(emb + (size_t)tk * E_ + lane * 4);
        }

        f32x4 acc0[2] = {{0.f,0.f,0.f,0.f},{0.f,0.f,0.f,0.f}};
        f32x4 accp[2];
        #pragma unroll
        for (int tc = 0; tc < 2; ++tc)
            accp[tc] = (f32x4){b0r[tc], b0r[tc], b0r[tc], b0r[tc]};
        #pragma unroll
        for (int kk = 0; kk < 8; ++kk)
            #pragma unroll
            for (int tc = 0; tc < 2; ++tc) {
                acc0[tc] = __builtin_amdgcn_mfma_f32_16x16x32_bf16(
                    Af[kk], Br[tc][kk], acc0[tc], 0, 0, 0);
                accp[tc] = __builtin_amdgcn_mfma_f32_16x16x32_bf16(
                    Ef[kk], Bi[tc][kk], accp[tc], 0, 0, 0);
            }

        if (have_next) stage_row_rm(eb[rb ^ 1], slot, lane, ev);

        #pragma unroll
        for (int tc = 0; tc < 2; ++tc) {
            const int c = n0 + tc * 16 + l15;
            #pragma unroll
            for (int reg = 0; reg < 2; ++reg) {
                const int b = bg + quad * 2 + reg;
                const float pre = accp[tc][reg] + acc0[tc][reg];
                const float hn  = h_prev[tc][reg]
                                + (fast_tanh(pre) - h_prev[tc][reg]) * inv_tau[tc];
                h_prev[tc][reg] = hn;
                hb[rb ^ 1][woff[tc][reg]] = f2bf(hn);
                // agent-scope: cross-XCD visible once retired (r8 mechanism)
                __hip_atomic_store(&out[(size_t)(b * T_ + t) * OW_ + c], hn,
                                   __ATOMIC_RELAXED, __HIP_MEMORY_SCOPE_AGENT);
            }
        }

        if ((t & 7) == 7) {
            __syncthreads();   // drains vmcnt -> h0 rows <= t retired
            if (tid == 0)
                __hip_atomic_store(flag, MAGIC + (unsigned)((t + 1) >> 3),
                                   __ATOMIC_RELEASE, __HIP_MEMORY_SCOPE_AGENT);
        } else {
            LGKM_BARRIER();
        }
    }
}

__device__ __forceinline__ void consumer_core(
    int grp, ushort_t (*hb)[4096], ushort_t (*eb)[16][LP],
    const float* Wr1, const float* m1, const float* Wi1,
    const float* b1v, const float* tau1,
    float* out, unsigned int* flag)
{
    const int tid  = threadIdx.x;
    const int lane = tid & 63;
    const int wv   = tid >> 6;
    const int quad = lane >> 4;
    const int l15  = lane & 15;
    const int n0   = wv * 32;
    const int bg   = grp * 8;
    const int slot = (wv >> 1) * 4 + (wv & 1);

    bf16x8 Br[2][8], Bi[2][8];
    float  b1r[2], inv_tau[2], h_prev[2][2];
    #pragma unroll
    for (int tc = 0; tc < 2; ++tc) {
        const int c = n0 + tc * 16 + l15;
        b1r[tc] = b1v[c];
        inv_tau[tc] = 1.0f / (logf(1.0f + __expf(tau1[c])) + 0.1f);
        h_prev[tc][0] = h_prev[tc][1] = 0.f;
        #pragma unroll
        for (int kk = 0; kk < 8; ++kk) {
            Br[tc][kk] = load_bfrag(Wr1, m1, (size_t)c * H_ + kk * 32 + quad * 8);
            Bi[tc][kk] = load_bfrag(Wi1, nullptr, (size_t)c * H_ + kk * 32 + quad * 8);
        }
    }

    int woff[2][2];
    #pragma unroll
    for (int tc = 0; tc < 2; ++tc)
        #pragma unroll
        for (int reg = 0; reg < 2; ++reg)
            woff[tc][reg] = a_off(quad * 4 + reg, n0 + tc * 16 + l15);
    const int ab    = ((l15 & 2) == 0) ? (lane * 8) : 0;
    const int ebase = ((l15 & 2) == 0) ? (l15 * LP + quad * 8) : 0;

    for (int i = tid; i < 4096; i += 512)
        ((unsigned int*)&hb[0][0])[i] = 0u;   // h1(-1) = 0

    // prologue: wait chunk 1 (h0 rows 0..7), stage h0(0)
    if (tid == 0) {
        for (;;) {
            unsigned d = __hip_atomic_load(flag, __ATOMIC_ACQUIRE,
                                           __HIP_MEMORY_SCOPE_AGENT) - MAGIC;
            if (d >= 1u && d <= 16u) break;
            __builtin_amdgcn_s_sleep(2);
        }
    }
    __syncthreads();
    {
        float4 v = *(const float4*)(out + (size_t)((bg + wv) * T_ + 0) * OW_
                                    + lane * 4);
        stage_row_rm(eb[0], slot, lane, v);
    }
    __syncthreads();

    for (int t = 0; t < T_; ++t) {
        const int rb = t & 1;

        #pragma unroll
        for (int tc = 0; tc < 2; ++tc)
            #pragma unroll
            for (int kk = 0; kk < 8; ++kk) { PIN_FRAG(Br[tc][kk]); PIN_FRAG(Bi[tc][kk]); }

        bf16x8 Af[8], Ef[8];
        {
            const ushort_t* a0 = &hb[rb][0];
            const ushort_t* e0 = &eb[rb][0][0];
            #pragma unroll
            for (int kk = 0; kk < 8; ++kk) {
                Af[kk] = *(const bf16x8*)(a0 + ab + kk * 512);
                Ef[kk] = *(const bf16x8*)(e0 + ebase + kk * 32);
            }
        }

        // early prefetch of h0(t+1) when flag-covered (within chunk)
        const bool have_next = (t + 1 < T_);
        const bool edge = ((t & 7) == 7);
        float4 hv;
        if (have_next && !edge)
            hv = *(const float4*)(out + (size_t)((bg + wv) * T_ + t + 1) * OW_
                                  + lane * 4);

        f32x4 acc1[2] = {{0.f,0.f,0.f,0.f},{0.f,0.f,0.f,0.f}};
        f32x4 acc2[2];
        #pragma unroll
        for (int tc = 0; tc < 2; ++tc)
            acc2[tc] = (f32x4){b1r[tc], b1r[tc], b1r[tc], b1r[tc]};
        #pragma unroll
        for (int kk = 0; kk < 8; ++kk)
            #pragma unroll
            for (int tc = 0; tc < 2; ++tc) {
                acc1[tc] = __builtin_amdgcn_mfma_f32_16x16x32_bf16(
                    Af[kk], Br[tc][kk], acc1[tc], 0, 0, 0);
                acc2[tc] = __builtin_amdgcn_mfma_f32_16x16x32_bf16(
                    Ef[kk], Bi[tc][kk], acc2[tc], 0, 0, 0);
            }

        #pragma unroll
        for (int tc = 0; tc < 2; ++tc) {
            const int c = n0 + tc * 16 + l15;
            #pragma unroll
            for (int reg = 0; reg < 2; ++reg) {
                const int b = bg + quad * 2 + reg;
                const float pre = acc2[tc][reg] + acc1[tc][reg];
                const float hn  = h_prev[tc][reg]
                                + (fast_tanh(pre) - h_prev[tc][reg]) * inv_tau[tc];
                h_prev[tc][reg] = hn;
                hb[rb ^ 1][woff[tc][reg]] = f2bf(hn);
                out[(size_t)(b * T_ + t) * OW_ + H_ + c] = hn;   // h1 plain store
            }
        }

        if (have_next) {
            if (edge) {   // next chunk: wait flag, then (covered) load h0(t+1)
                if (tid == 0) {
                    const unsigned need = (unsigned)((t + 1) >> 3) + 1u;
                    for (;;) {
                        unsigned d = __hip_atomic_load(flag, __ATOMIC_ACQUIRE,
                                                       __HIP_MEMORY_SCOPE_AGENT) - MAGIC;
                        if (d >= need && d <= 16u) break;
                        __builtin_amdgcn_s_sleep(2);
                    }
                }
                __syncthreads();
                hv = *(const float4*)(out + (size_t)((bg + wv) * T_ + t + 1) * OW_
                                      + lane * 4);
            }
            stage_row_rm(eb[rb ^ 1], slot, lane, hv);
            LGKM_BARRIER();
        }
    }
}

__global__ __launch_bounds__(512, 1)
void ltc_fused(const int* __restrict__ tokens, const float* __restrict__ emb,
               const float* __restrict__ Wi0, const float* __restrict__ b0v,
               const float* __restrict__ Wr0, const float* __restrict__ m0,
               const float* __restrict__ t0,
               const float* __restrict__ Wi1, const float* __restrict__ b1v,
               const float* __restrict__ Wr1, const float* __restrict__ m1,
               const float* __restrict__ t1,
               float* out, unsigned int* flags)
{
    __shared__ __align__(16) ushort_t hb[2][4096];
    __shared__ __align__(16) ushort_t eb[2][16][LP];
    if (blockIdx.x < 8)
        producer_core(blockIdx.x, hb, eb, tokens, emb,
                      Wr0, m0, Wi0, b0v, t0, out, flags + blockIdx.x);
    else
        consumer_core(blockIdx.x - 8, hb, eb,
                      Wr1, m1, Wi1, b1v, t1, out, flags + blockIdx.x - 8);
}

// ---------------------------------------------------------------------------
// Fallback path (ws too small for flags): r13-proven standalone scan + proj.
// ---------------------------------------------------------------------------
__global__ __launch_bounds__(512, 1)
void ltc_single(const float* xp, int xp_stride, int xp_col,
                float* hout, int out_col,
                const float* __restrict__ Wr, const float* __restrict__ mk,
                const float* __restrict__ tu)
{
    __shared__ __align__(16) ushort_t hb[2][4096];
    const int tid  = threadIdx.x;
    const int lane = tid & 63;
    const int wv   = tid >> 6;
    const int quad = lane >> 4;
    const int l15  = lane & 15;
    const int n0   = wv * 32;
    const int bg   = blockIdx.x * 8;

    bf16x8 Bf[2][8];
    #pragma unroll
    for (int tc = 0; tc < 2; ++tc)
        #pragma unroll
        for (int kk = 0; kk < 8; ++kk)
            Bf[tc][kk] = load_bfrag(Wr, mk,
                (size_t)(n0 + tc * 16 + l15) * H_ + kk * 32 + quad * 8);

    float inv_tau[2], h_prev[2][2], xp_c[2][2], xp_n[2][2], xp_nn[2][2];
    #pragma unroll
    for (int tc = 0; tc < 2; ++tc) {
        inv_tau[tc] = 1.0f / (logf(1.0f + __expf(tu[n0 + tc * 16 + l15])) + 0.1f);
        #pragma unroll
        for (int reg = 0; reg < 2; ++reg) {
            h_prev[tc][reg] = 0.f; xp_c[tc][reg] = xp_n[tc][reg] = xp_nn[tc][reg] = 0.f;
            const int b = bg + quad * 2 + reg;
            const int c = n0 + tc * 16 + l15;
            xp_c[tc][reg] = xp[(size_t)(b * T_ + 0) * xp_stride + xp_col + c];
            xp_n[tc][reg] = xp[(size_t)(b * T_ + 1) * xp_stride + xp_col + c];
        }
    }
    int woff[2][2];
    #pragma unroll
    for (int tc = 0; tc < 2; ++tc)
        #pragma unroll
        for (int reg = 0; reg < 2; ++reg)
            woff[tc][reg] = a_off(quad * 4 + reg, n0 + tc * 16 + l15);
    const int ab = ((l15 & 2) == 0) ? (lane * 8) : 0;

    for (int i = tid; i < 4096; i += 512)
        ((unsigned int*)&hb[0][0])[i] = 0u;
    __syncthreads();

    for (int t = 0; t < T_; ++t) {
        const int rb = t & 1;
        bf16x8 Af[8];
        {
            const ushort_t* a0 = &hb[rb][0];
            #pragma unroll
            for (int kk = 0; kk < 8; ++kk)
                Af[kk] = *(const bf16x8*)(a0 + ab + kk * 512);
        }
        if (t + 2 < T_) {
            #pragma unroll
            for (int tc = 0; tc < 2; ++tc)
                #pragma unroll
                for (int reg = 0; reg < 2; ++reg) {
                    const int b = bg + quad * 2 + reg;
                    xp_nn[tc][reg] = xp[(size_t)(b * T_ + t + 2) * xp_stride
                                        + xp_col + n0 + tc * 16 + l15];
                }
        }
        f32x4 acc[2] = {{0.f,0.f,0.f,0.f},{0.f,0.f,0.f,0.f}};
        #pragma unroll
        for (int kk = 0; kk < 8; ++kk)
            #pragma unroll
            for (int tc = 0; tc < 2; ++tc)
                acc[tc] = __builtin_amdgcn_mfma_f32_16x16x32_bf16(
                    Af[kk], Bf[tc][kk], acc[tc], 0, 0, 0);
        #pragma unroll
        for (int tc = 0; tc < 2; ++tc) {
            const int c = n0 + tc * 16 + l15;
            #pragma unroll
            for (int reg = 0; reg < 2; ++reg) {
                const int b = bg + quad * 2 + reg;
                const float pre = xp_c[tc][reg] + acc[tc][reg];
                const float hn  = h_prev[tc][reg]
                                + (fast_tanh(pre) - h_prev[tc][reg]) * inv_tau[tc];
                h_prev[tc][reg] = hn;
                hb[rb ^ 1][woff[tc][reg]] = f2bf(hn);
                hout[(size_t)(b * T_ + t) * OW_ + out_col + c] = hn;
            }
        }
        #pragma unroll
        for (int tc = 0; tc < 2; ++tc)
            #pragma unroll
            for (int reg = 0; reg < 2; ++reg) {
                xp_c[tc][reg] = xp_n[tc][reg];
                xp_n[tc][reg] = xp_nn[tc][reg];
            }
        if (t + 1 < T_) LGKM_BARRIER();
    }
}

__global__ __launch_bounds__(512, 2)
void proj_mfma(const float* __restrict__ src, int src_stride, int src_col,
               const int* __restrict__ tok,
               const float* __restrict__ Wi,
               const float* __restrict__ bias,
               float* __restrict__ dst, int dst_stride, int dst_col)
{
    const int tid  = threadIdx.x;
    const int lane = tid & 63;
    const int wv   = tid >> 6;
    const int quad = lane >> 4;
    const int l15  = lane & 15;
    const int n0   = wv * 32;

    __shared__ __align__(16) ushort_t As[32][LP];

    bf16x8 Bf[2][8];
    float  bj[2];
    #pragma unroll
    for (int tc = 0; tc < 2; ++tc) {
        const int n = n0 + tc * 16 + l15;
        bj[tc] = bias[n];
        #pragma unroll
        for (int kk = 0; kk < 8; ++kk)
            Bf[tc][kk] = load_bfrag(Wi, nullptr, (size_t)n * H_ + kk * 32 + quad * 8);
    }

    const int r0 = blockIdx.x * 32;
    {
        const int row = tid >> 4;
        const int seg = tid & 15;
        const size_t sb = (tok ? (size_t)tok[r0 + row] : (size_t)(r0 + row))
                          * src_stride + src_col + seg * 16;
        union { uint4 q[2]; ushort_t u[16]; } p;
        #pragma unroll
        for (int h = 0; h < 2; ++h) {
            float4 f0 = *(const float4*)(src + sb + h * 8);
            float4 f1 = *(const float4*)(src + sb + h * 8 + 4);
            p.u[h*8+0] = f2bf(f0.x); p.u[h*8+1] = f2bf(f0.y);
            p.u[h*8+2] = f2bf(f0.z); p.u[h*8+3] = f2bf(f0.w);
            p.u[h*8+4] = f2bf(f1.x); p.u[h*8+5] = f2bf(f1.y);
            p.u[h*8+6] = f2bf(f1.z); p.u[h*8+7] = f2bf(f1.w);
        }
        *(uint4*)&As[row][seg * 16]     = p.q[0];
        *(uint4*)&As[row][seg * 16 + 8] = p.q[1];
    }
    __syncthreads();

    #pragma unroll
    for (int rt = 0; rt < 2; ++rt) {
        bf16x8 Af[8];
        #pragma unroll
        for (int kk = 0; kk < 8; ++kk)
            Af[kk] = *(const bf16x8*)&As[rt * 16 + l15][kk * 32 + quad * 8];

        f32x4 acc[2] = {{bj[0],bj[0],bj[0],bj[0]}, {bj[1],bj[1],bj[1],bj[1]}};
        #pragma unroll
        for (int kk = 0; kk < 8; ++kk)
            #pragma unroll
            for (int tc = 0; tc < 2; ++tc)
                acc[tc] = __builtin_amdgcn_mfma_f32_16x16x32_bf16(
                    Af[kk], Bf[tc][kk], acc[tc], 0, 0, 0);

        #pragma unroll
        for (int tc = 0; tc < 2; ++tc) {
            const int c = n0 + tc * 16 + l15;
            #pragma unroll
            for (int reg = 0; reg < 4; ++reg) {
                const int r = r0 + rt * 16 + quad * 4 + reg;
                dst[(size_t)r * dst_stride + dst_col + c] = acc[tc][reg];
            }
        }
    }
}

extern "C" void kernel_launch(void* const* d_in, const int* in_sizes, int n_in,
                              void* d_out, int out_size, void* d_ws, size_t ws_size,
                              hipStream_t stream)
{
    const int*   tokens = (const int*)d_in[0];
    const float* emb    = (const float*)d_in[1];
    const float* W_in0  = (const float*)d_in[2];
    const float* W_rec0 = (const float*)d_in[3];
    const float* b0     = (const float*)d_in[4];
    const float* tau0   = (const float*)d_in[5];
    const float* mask0  = (const float*)d_in[6];
    const float* W_in1  = (const float*)d_in[7];
    const float* W_rec1 = (const float*)d_in[8];
    const float* b1     = (const float*)d_in[9];
    const float* tau1   = (const float*)d_in[10];
    const float* mask1  = (const float*)d_in[11];
    float* out = (float*)d_out;    // [8192, 512] f32
    (void)in_sizes; (void)n_in; (void)out_size;

    if (ws_size >= 64) {
        // flags arrive poisoned (0xAA..) each launch; consumers' window check
        // treats poison as not-ready; producers overwrite with MAGIC+c.
        unsigned int* flags = (unsigned int*)d_ws;
        ltc_fused<<<dim3(16), dim3(512), 0, stream>>>(
            tokens, emb, W_in0, b0, W_rec0, mask0, tau0,
            W_in1, b1, W_rec1, mask1, tau1, out, flags);
    } else {
        proj_mfma<<<dim3(256), dim3(512), 0, stream>>>(
            emb, E_, 0, tokens, W_in0, b0, out, OW_, H_);
        ltc_single<<<dim3(8), dim3(512), 0, stream>>>(
            out, OW_, H_, out, 0, W_rec0, mask0, tau0);
        proj_mfma<<<dim3(256), dim3(512), 0, stream>>>(
            out, OW_, 0, nullptr, W_in1, b1, out, OW_, H_);
        ltc_single<<<dim3(8), dim3(512), 0, stream>>>(
            out, OW_, H_, out, H_, W_rec1, mask1, tau1);
    }
}

// Round 8
// 262.189 us; speedup vs baseline: 1.1283x; 1.1159x over previous
//
#include <hip/hip_runtime.h>
#include <hip/hip_bf16.h>

#define B_ 64
#define T_ 128
#define E_ 256
#define H_ 256
#define OW_ 512   // output row width = 2*H (elements)
#define LP 264    // LDS bf16 row pitch for proj staging (elements)
#define MAGIC 0x5AD00000u

typedef unsigned short ushort_t;
typedef __attribute__((ext_vector_type(8))) short bf16x8;   // 8 bf16 = 4 VGPRs
typedef __attribute__((ext_vector_type(4))) float f32x4;    // 4 f32 acc

// Workgroup barrier WITHOUT the compiler's vmcnt(0) drain (validated r7/r8).
#define LGKM_BARRIER() asm volatile("s_waitcnt lgkmcnt(0)\n\ts_barrier" ::: "memory")
// Keep weight fragments loop-carried (r12: -6%, kept).
#define PIN_FRAG(x) asm volatile("" : "+v"(x))

__device__ __forceinline__ ushort_t f2bf(float f) {
    unsigned int x = __float_as_uint(f);
    unsigned int r = x + 0x7FFFu + ((x >> 16) & 1u);
    return (ushort_t)(r >> 16);
}
__device__ __forceinline__ float fast_tanh(float x) {
    float e = __expf(2.0f * x);
    return 1.0f - 2.0f * __builtin_amdgcn_rcpf(e + 1.0f);
}
__device__ __forceinline__ bf16x8 load_bfrag(const float* W, const float* M,
                                             size_t base) {
    float4 a = *(const float4*)(W + base);
    float4 b = *(const float4*)(W + base + 4);
    if (M) {
        float4 ma = *(const float4*)(M + base);
        float4 mb = *(const float4*)(M + base + 4);
        a.x *= ma.x; a.y *= ma.y; a.z *= ma.z; a.w *= ma.w;
        b.x *= mb.x; b.y *= mb.y; b.z *= mb.z; b.w *= mb.w;
    }
    union { bf16x8 v; ushort_t u[8]; } r;
    r.u[0] = f2bf(a.x); r.u[1] = f2bf(a.y); r.u[2] = f2bf(a.z); r.u[3] = f2bf(a.w);
    r.u[4] = f2bf(b.x); r.u[5] = f2bf(b.y); r.u[6] = f2bf(b.z); r.u[7] = f2bf(b.w);
    return r.v;
}

// Fragment-major LDS A-layout for hb (r9-verified): element (r,k) at
//   off = (k>>5)*512 + ((k>>3)&3)*128 + r*8 + (k&7)
// Reader lane L reads frag kk as b128 at element L*8 + kk*512 (linear,
// conflict-free). Pad-row lanes ((l15&2)!=0; C rows discarded) broadcast.
__device__ __forceinline__ int a_off(int r, int k) {
    return ((k >> 5) << 9) + (((k >> 3) & 3) << 7) + (r << 3) + (k & 7);
}

// ---------------------------------------------------------------------------
// scan_core<FUSE,WAIT>: the r12-validated structure (149.6us scan), UNCHANGED
// except for optional proj0 window flags (projf != nullptr on the producer):
// producer spins (poison-tolerant, ==MAGIC) for the 8 proj blocks covering
// a 32-step xp0 window before prefetching into it (t = prologue, 30, 62, 94).
// Batch row i at A-slot (i>>1)*4+(i&1); C rows quad*4+reg (reg<2) ->
// lane(quad,l15) owns batches {quad*2,quad*2+1} x cols {wv*32+tc*16+l15}.
// FUSE: computes xp1(t-1) = h0(t-1)@Wf^T + bf with the same A-frags,
//   agent-scope stores to xf, publishes 8-row chunks via vmcnt-draining
//   __syncthreads + release flag.  WAIT: spins for each 8-row xp chunk.
// ---------------------------------------------------------------------------
template<bool FUSE, bool WAIT>
__device__ __forceinline__ void scan_core(
    int grp, ushort_t (*hb)[4096],
    const float* xp, int xp_stride, int xp_col,
    float* hout, int out_col,
    const float* Wrec, const float* Wmask, const float* tau_raw,
    const float* Wf, const float* bfv, float* xf,
    unsigned int* flag, const unsigned int* projf)
{
    const int tid  = threadIdx.x;
    const int lane = tid & 63;
    const int wv   = tid >> 6;     // 0..7
    const int quad = lane >> 4;
    const int l15  = lane & 15;
    const int n0   = wv * 32;
    const int bg   = grp * 8;

    bf16x8 Bf[2][8];
    #pragma unroll
    for (int tc = 0; tc < 2; ++tc)
        #pragma unroll
        for (int kk = 0; kk < 8; ++kk)
            Bf[tc][kk] = load_bfrag(Wrec, Wmask,
                (size_t)(n0 + tc * 16 + l15) * H_ + kk * 32 + quad * 8);

    bf16x8 Bf2[2][8];
    float  b2[2] = {0.f, 0.f};
    if (FUSE) {
        #pragma unroll
        for (int tc = 0; tc < 2; ++tc) {
            b2[tc] = bfv[n0 + tc * 16 + l15];
            #pragma unroll
            for (int kk = 0; kk < 8; ++kk)
                Bf2[tc][kk] = load_bfrag(Wf, nullptr,
                    (size_t)(n0 + tc * 16 + l15) * H_ + kk * 32 + quad * 8);
        }
    }

    float inv_tau[2], h_prev[2][2];
    float xp_c[2][2], xp_n[2][2], xp_nn[2][2];
    #pragma unroll
    for (int tc = 0; tc < 2; ++tc) {
        inv_tau[tc] = 1.0f / (logf(1.0f + __expf(tau_raw[n0 + tc * 16 + l15])) + 0.1f);
        #pragma unroll
        for (int reg = 0; reg < 2; ++reg) {
            h_prev[tc][reg] = 0.0f;
            xp_c[tc][reg] = xp_n[tc][reg] = xp_nn[tc][reg] = 0.0f;
        }
    }

    int woff[2][2];
    #pragma unroll
    for (int tc = 0; tc < 2; ++tc)
        #pragma unroll
        for (int reg = 0; reg < 2; ++reg)
            woff[tc][reg] = a_off(quad * 4 + reg, n0 + tc * 16 + l15);
    const int ab = ((l15 & 2) == 0) ? (lane * 8) : 0;

    if (!WAIT) {   // prologue loads for t=0,1 (WAIT loads at chunk tops)
        if (FUSE && projf != nullptr) {    // xp0 window 0 ready?
            if (tid < 8) {
                const unsigned p = (unsigned)(bg + tid);   // w=0 block b
                for (;;) {
                    unsigned v = __hip_atomic_load(&projf[p], __ATOMIC_ACQUIRE,
                                                   __HIP_MEMORY_SCOPE_AGENT);
                    if (v == MAGIC) break;
                    __builtin_amdgcn_s_sleep(2);
                }
            }
            __syncthreads();
        }
        #pragma unroll
        for (int tc = 0; tc < 2; ++tc)
            #pragma unroll
            for (int reg = 0; reg < 2; ++reg) {
                const int b = bg + quad * 2 + reg;
                const int c = n0 + tc * 16 + l15;
                xp_c[tc][reg] = xp[(size_t)(b * T_ + 0) * xp_stride + xp_col + c];
                xp_n[tc][reg] = xp[(size_t)(b * T_ + 1) * xp_stride + xp_col + c];
            }
    }

    for (int i = tid; i < 4096; i += 512)
        ((unsigned int*)&hb[0][0])[i] = 0u;   // zero both buffers (16 KB)
    __syncthreads();

    const int tmax = FUSE ? T_ : (T_ - 1);
    for (int t = 0; t <= tmax; ++t) {
        const int rb = t & 1;

        #pragma unroll
        for (int tc = 0; tc < 2; ++tc)
            #pragma unroll
            for (int kk = 0; kk < 8; ++kk) {
                PIN_FRAG(Bf[tc][kk]);
                if (FUSE) PIN_FRAG(Bf2[tc][kk]);
            }

        if (WAIT && t < T_ && (t & 7) == 0) {
            if (tid == 0) {
                const unsigned need = (unsigned)(t >> 3) + 1u;
                for (;;) {
                    unsigned d = __hip_atomic_load(flag, __ATOMIC_ACQUIRE,
                                                   __HIP_MEMORY_SCOPE_AGENT) - MAGIC;
                    if (d >= need && d <= 16u) break;
                    __builtin_amdgcn_s_sleep(2);
                }
            }
            __syncthreads();
            #pragma unroll
            for (int tc = 0; tc < 2; ++tc)
                #pragma unroll
                for (int reg = 0; reg < 2; ++reg) {
                    const int b = bg + quad * 2 + reg;
                    xp_c[tc][reg] = xp[(size_t)(b * T_ + t) * xp_stride + xp_col
                                       + n0 + tc * 16 + l15];
                }
        }

        // A fragments (h(t-1)); shared by recurrence and fused projection.
        bf16x8 Af[8];
        {
            const ushort_t* a0 = &hb[rb][0];
            #pragma unroll
            for (int kk = 0; kk < 8; ++kk)
                Af[kk] = *(const bf16x8*)(a0 + ab + kk * 512);
        }

        if (t < T_) {
            // prefetch
            if (WAIT) {
                if ((t & 7) != 7 && t + 1 < T_) {
                    #pragma unroll
                    for (int tc = 0; tc < 2; ++tc)
                        #pragma unroll
                        for (int reg = 0; reg < 2; ++reg) {
                            const int b = bg + quad * 2 + reg;
                            xp_n[tc][reg] = xp[(size_t)(b * T_ + t + 1) * xp_stride
                                               + xp_col + n0 + tc * 16 + l15];
                        }
                }
            } else if (t + 2 < T_) {
                if (FUSE && projf != nullptr && ((t + 2) & 31) == 0) {
                    // entering a new 32-step xp0 window: proj blocks done?
                    if (tid < 8) {
                        const unsigned p = (unsigned)(((t + 2) >> 5) * 64 + bg + tid);
                        for (;;) {
                            unsigned v = __hip_atomic_load(&projf[p],
                                                           __ATOMIC_ACQUIRE,
                                                           __HIP_MEMORY_SCOPE_AGENT);
                            if (v == MAGIC) break;
                            __builtin_amdgcn_s_sleep(2);
                        }
                    }
                    __syncthreads();
                }
                #pragma unroll
                for (int tc = 0; tc < 2; ++tc)
                    #pragma unroll
                    for (int reg = 0; reg < 2; ++reg) {
                        const int b = bg + quad * 2 + reg;
                        xp_nn[tc][reg] = xp[(size_t)(b * T_ + t + 2) * xp_stride
                                            + xp_col + n0 + tc * 16 + l15];
                    }
            }

            f32x4 acc[2] = {{0.f,0.f,0.f,0.f},{0.f,0.f,0.f,0.f}};
            #pragma unroll
            for (int kk = 0; kk < 8; ++kk)
                #pragma unroll
                for (int tc = 0; tc < 2; ++tc)
                    acc[tc] = __builtin_amdgcn_mfma_f32_16x16x32_bf16(
                        Af[kk], Bf[tc][kk], acc[tc], 0, 0, 0);

            #pragma unroll
            for (int tc = 0; tc < 2; ++tc) {
                const int c = n0 + tc * 16 + l15;
                #pragma unroll
                for (int reg = 0; reg < 2; ++reg) {
                    const int b = bg + quad * 2 + reg;
                    const float pre = xp_c[tc][reg] + acc[tc][reg];
                    const float hn  = h_prev[tc][reg]
                                    + (fast_tanh(pre) - h_prev[tc][reg]) * inv_tau[tc];
                    h_prev[tc][reg] = hn;
                    hb[rb ^ 1][woff[tc][reg]] = f2bf(hn);
                    hout[(size_t)(b * T_ + t) * OW_ + out_col + c] = hn;
                }
            }
            if (WAIT) {
                if ((t & 7) != 7) {
                    #pragma unroll
                    for (int tc = 0; tc < 2; ++tc)
                        #pragma unroll
                        for (int reg = 0; reg < 2; ++reg)
                            xp_c[tc][reg] = xp_n[tc][reg];
                }
            } else {
                #pragma unroll
                for (int tc = 0; tc < 2; ++tc)
                    #pragma unroll
                    for (int reg = 0; reg < 2; ++reg) {
                        xp_c[tc][reg] = xp_n[tc][reg];
                        xp_n[tc][reg] = xp_nn[tc][reg];
                    }
            }
        }

        if (FUSE && t > 0) {
            f32x4 acc2[2];
            #pragma unroll
            for (int tc = 0; tc < 2; ++tc)
                acc2[tc] = (f32x4){b2[tc], b2[tc], b2[tc], b2[tc]};
            #pragma unroll
            for (int kk = 0; kk < 8; ++kk)
                #pragma unroll
                for (int tc = 0; tc < 2; ++tc)
                    acc2[tc] = __builtin_amdgcn_mfma_f32_16x16x32_bf16(
                        Af[kk], Bf2[tc][kk], acc2[tc], 0, 0, 0);
            #pragma unroll
            for (int tc = 0; tc < 2; ++tc) {
                const int c = n0 + tc * 16 + l15;
                #pragma unroll
                for (int reg = 0; reg < 2; ++reg) {
                    const int b = bg + quad * 2 + reg;
                    // agent-scope store: cross-XCD visible once retired
                    __hip_atomic_store(&xf[(size_t)(b * T_ + t - 1) * H_ + c],
                                       acc2[tc][reg],
                                       __ATOMIC_RELAXED, __HIP_MEMORY_SCOPE_AGENT);
                }
            }
        }

        if (FUSE && t > 0 && (t & 7) == 0) {
            __syncthreads();   // drains vmcnt -> all xf stores of rows < t retired
            if (tid == 0)
                __hip_atomic_store(flag, MAGIC + (unsigned)(t >> 3),
                                   __ATOMIC_RELEASE, __HIP_MEMORY_SCOPE_AGENT);
        } else if (t < tmax) {
            LGKM_BARRIER();
        }
    }
}

// ---------------------------------------------------------------------------
// proj body: dst[r][dst_col+n] = bias[n] + src[row(r)] @ Wi^T  (32 rows).
// done != nullptr: agent-scope stores (cross-XCD visible within the same
// dispatch) + per-block done flag (MAGIC, release, after vmcnt-drain sync).
// ---------------------------------------------------------------------------
__device__ __forceinline__ void proj_body(
    int r0, const float* __restrict__ src, int src_stride, int src_col,
    const int* __restrict__ tok,
    const float* __restrict__ Wi, const float* __restrict__ bias,
    float* __restrict__ dst, int dst_stride, int dst_col,
    unsigned int* done, int done_idx)
{
    const int tid  = threadIdx.x;
    const int lane = tid & 63;
    const int wv   = tid >> 6;
    const int quad = lane >> 4;
    const int l15  = lane & 15;
    const int n0   = wv * 32;

    __shared__ __align__(16) ushort_t As[32][LP];

    bf16x8 Bf[2][8];
    float  bj[2];
    #pragma unroll
    for (int tc = 0; tc < 2; ++tc) {
        const int n = n0 + tc * 16 + l15;
        bj[tc] = bias[n];
        #pragma unroll
        for (int kk = 0; kk < 8; ++kk)
            Bf[tc][kk] = load_bfrag(Wi, nullptr, (size_t)n * H_ + kk * 32 + quad * 8);
    }

    {
        const int row = tid >> 4;
        const int seg = tid & 15;
        const size_t sb = (tok ? (size_t)tok[r0 + row] : (size_t)(r0 + row))
                          * src_stride + src_col + seg * 16;
        union { uint4 q[2]; ushort_t u[16]; } p;
        #pragma unroll
        for (int h = 0; h < 2; ++h) {
            float4 f0 = *(const float4*)(src + sb + h * 8);
            float4 f1 = *(const float4*)(src + sb + h * 8 + 4);
            p.u[h*8+0] = f2bf(f0.x); p.u[h*8+1] = f2bf(f0.y);
            p.u[h*8+2] = f2bf(f0.z); p.u[h*8+3] = f2bf(f0.w);
            p.u[h*8+4] = f2bf(f1.x); p.u[h*8+5] = f2bf(f1.y);
            p.u[h*8+6] = f2bf(f1.z); p.u[h*8+7] = f2bf(f1.w);
        }
        *(uint4*)&As[row][seg * 16]     = p.q[0];
        *(uint4*)&As[row][seg * 16 + 8] = p.q[1];
    }
    __syncthreads();

    #pragma unroll
    for (int rt = 0; rt < 2; ++rt) {
        bf16x8 Af[8];
        #pragma unroll
        for (int kk = 0; kk < 8; ++kk)
            Af[kk] = *(const bf16x8*)&As[rt * 16 + l15][kk * 32 + quad * 8];

        f32x4 acc[2] = {{bj[0],bj[0],bj[0],bj[0]}, {bj[1],bj[1],bj[1],bj[1]}};
        #pragma unroll
        for (int kk = 0; kk < 8; ++kk)
            #pragma unroll
            for (int tc = 0; tc < 2; ++tc)
                acc[tc] = __builtin_amdgcn_mfma_f32_16x16x32_bf16(
                    Af[kk], Bf[tc][kk], acc[tc], 0, 0, 0);

        #pragma unroll
        for (int tc = 0; tc < 2; ++tc) {
            const int c = n0 + tc * 16 + l15;
            #pragma unroll
            for (int reg = 0; reg < 4; ++reg) {
                const int r = r0 + rt * 16 + quad * 4 + reg;
                if (done)
                    __hip_atomic_store(&dst[(size_t)r * dst_stride + dst_col + c],
                                       acc[tc][reg],
                                       __ATOMIC_RELAXED, __HIP_MEMORY_SCOPE_AGENT);
                else
                    dst[(size_t)r * dst_stride + dst_col + c] = acc[tc][reg];
            }
        }
    }

    if (done) {
        __syncthreads();   // drains vmcnt -> all xp0 stores of this block retired
        if (tid == 0)
            __hip_atomic_store(&done[done_idx], MAGIC,
                               __ATOMIC_RELEASE, __HIP_MEMORY_SCOPE_AGENT);
    }
}

// ---------------------------------------------------------------------------
// Single merged dispatch: blocks 0..7 producers, 8..15 consumers (the r12
// dual-scan), 16..271 proj0 blocks running CONCURRENTLY on the other CUs.
// proj block p covers rows (b = p&63, t-window w = p>>6) -> w=0 blocks carry
// the lowest IDs = dispatched first (producers need window 0 by step ~30).
// ---------------------------------------------------------------------------
__global__ __launch_bounds__(512, 1)
void ltc_all(const int* __restrict__ tokens, const float* __restrict__ emb,
             const float* __restrict__ Wi0, const float* __restrict__ b0v,
             const float* __restrict__ Wr0, const float* __restrict__ m0,
             const float* __restrict__ t0,
             const float* __restrict__ Wi1, const float* __restrict__ b1v,
             const float* __restrict__ Wr1, const float* __restrict__ m1,
             const float* __restrict__ t1,
             float* out, float* xf, unsigned int* flags, unsigned int* projf)
{
    __shared__ __align__(16) ushort_t hb[2][4096];
    if (blockIdx.x < 8)
        scan_core<true, false>(blockIdx.x, hb,
                               out, OW_, H_,     // xp0 in out cols 256..511
                               out, 0,           // h0 -> cols 0..255
                               Wr0, m0, t0, Wi1, b1v, xf,
                               flags + blockIdx.x, projf);
    else if (blockIdx.x < 16)
        scan_core<false, true>(blockIdx.x - 8, hb,
                               xf, H_, 0,        // xp1 from workspace
                               out, H_,          // h1 -> cols 256..511
                               Wr1, m1, t1, nullptr, nullptr, nullptr,
                               flags + blockIdx.x - 8, nullptr);
    else {
        const int p  = blockIdx.x - 16;
        const int r0 = (p & 63) * T_ + (p >> 6) * 32;   // batch p&63, window p>>6
        proj_body(r0, emb, E_, 0, tokens, Wi0, b0v, out, OW_, H_, projf, p);
    }
}

// Two-dispatch variant (r12 behavior) for smaller workspaces.
__global__ __launch_bounds__(512, 1)
void ltc_dual(float* out,
              const float* __restrict__ Wr0, const float* __restrict__ m0,
              const float* __restrict__ t0,
              const float* __restrict__ Wi1, const float* __restrict__ b1v,
              const float* __restrict__ Wr1, const float* __restrict__ m1,
              const float* __restrict__ t1,
              float* xf, unsigned int* flags)
{
    __shared__ __align__(16) ushort_t hb[2][4096];
    if (blockIdx.x < 8)
        scan_core<true, false>(blockIdx.x, hb,
                               out, OW_, H_, out, 0,
                               Wr0, m0, t0, Wi1, b1v, xf,
                               flags + blockIdx.x, nullptr);
    else
        scan_core<false, true>(blockIdx.x - 8, hb,
                               xf, H_, 0, out, H_,
                               Wr1, m1, t1, nullptr, nullptr, nullptr,
                               flags + blockIdx.x - 8, nullptr);
}

// Fallback standalone scan (no workspace): alias-safe path.
__global__ __launch_bounds__(512, 1)
void ltc_single(const float* xp, int xp_stride, int xp_col,
                float* hout, int out_col,
                const float* __restrict__ Wr, const float* __restrict__ mk,
                const float* __restrict__ tu)
{
    __shared__ __align__(16) ushort_t hb[2][4096];
    scan_core<false, false>(blockIdx.x, hb, xp, xp_stride, xp_col,
                            hout, out_col, Wr, mk, tu,
                            nullptr, nullptr, nullptr, nullptr, nullptr);
}

__global__ __launch_bounds__(512, 2)
void proj_mfma(const float* __restrict__ src, int src_stride, int src_col,
               const int* __restrict__ tok,
               const float* __restrict__ Wi,
               const float* __restrict__ bias,
               float* __restrict__ dst, int dst_stride, int dst_col)
{
    proj_body(blockIdx.x * 32, src, src_stride, src_col, tok, Wi, bias,
              dst, dst_stride, dst_col, nullptr, 0);
}

extern "C" void kernel_launch(void* const* d_in, const int* in_sizes, int n_in,
                              void* d_out, int out_size, void* d_ws, size_t ws_size,
                              hipStream_t stream)
{
    const int*   tokens = (const int*)d_in[0];
    const float* emb    = (const float*)d_in[1];
    const float* W_in0  = (const float*)d_in[2];
    const float* W_rec0 = (const float*)d_in[3];
    const float* b0     = (const float*)d_in[4];
    const float* tau0   = (const float*)d_in[5];
    const float* mask0  = (const float*)d_in[6];
    const float* W_in1  = (const float*)d_in[7];
    const float* W_rec1 = (const float*)d_in[8];
    const float* b1     = (const float*)d_in[9];
    const float* tau1   = (const float*)d_in[10];
    const float* mask1  = (const float*)d_in[11];
    float* out = (float*)d_out;    // [8192, 512] f32
    (void)in_sizes; (void)n_in; (void)out_size;

    const size_t xf_elems = (size_t)B_ * T_ * H_;
    const size_t xf_bytes = xf_elems * sizeof(float);

    if (ws_size >= xf_bytes + 64 + 1024) {
        // ws: [xf f32 | 16 chunk flags | 256 proj done-flags]; all flags
        // arrive poisoned (0xAA..) each launch -> treated as not-ready.
        float* xf = (float*)d_ws;
        unsigned int* flags = (unsigned int*)((char*)d_ws + xf_bytes);
        unsigned int* projf = (unsigned int*)((char*)d_ws + xf_bytes + 64);
        ltc_all<<<dim3(272), dim3(512), 0, stream>>>(
            tokens, emb, W_in0, b0, W_rec0, mask0, tau0,
            W_in1, b1, W_rec1, mask1, tau1, out, xf, flags, projf);
    } else if (ws_size >= xf_bytes + 64) {
        float* xf = (float*)d_ws;
        unsigned int* flags = (unsigned int*)((char*)d_ws + xf_bytes);
        proj_mfma<<<dim3(256), dim3(512), 0, stream>>>(
            emb, E_, 0, tokens, W_in0, b0, out, OW_, H_);
        ltc_dual<<<dim3(16), dim3(512), 0, stream>>>(
            out, W_rec0, mask0, tau0, W_in1, b1, W_rec1, mask1, tau1, xf, flags);
    } else {
        proj_mfma<<<dim3(256), dim3(512), 0, stream>>>(
            emb, E_, 0, tokens, W_in0, b0, out, OW_, H_);
        ltc_single<<<dim3(8), dim3(512), 0, stream>>>(
            out, OW_, H_, out, 0, W_rec0, mask0, tau0);
        proj_mfma<<<dim3(256), dim3(512), 0, stream>>>(
            out, OW_, 0, nullptr, W_in1, b1, out, OW_, H_);
        ltc_single<<<dim3(8), dim3(512), 0, stream>>>(
            out, OW_, H_, out, H_, W_rec1, mask1, tau1);
    }
}

// Round 9
// 234.944 us; speedup vs baseline: 1.2592x; 1.1160x over previous
//
#include <hip/hip_runtime.h>
#include <hip/hip_bf16.h>

#define B_ 64
#define T_ 128
#define E_ 256
#define H_ 256
#define OW_ 512   // output row width = 2*H (elements)
#define LP 264    // LDS bf16 row pitch for row-major staging tiles (elements)
#define MAGIC 0x5AD00000u

typedef unsigned short ushort_t;
typedef __attribute__((ext_vector_type(8))) short bf16x8;   // 8 bf16 = 4 VGPRs
typedef __attribute__((ext_vector_type(4))) float f32x4;    // 4 f32 acc

// Workgroup barrier WITHOUT the compiler's vmcnt(0) drain (validated r7/r8).
#define LGKM_BARRIER() asm volatile("s_waitcnt lgkmcnt(0)\n\ts_barrier" ::: "memory")
// Keep weight fragments loop-carried (r12).
#define PIN_FRAG(x) asm volatile("" : "+v"(x))

__device__ __forceinline__ ushort_t f2bf(float f) {
    unsigned int x = __float_as_uint(f);
    unsigned int r = x + 0x7FFFu + ((x >> 16) & 1u);
    return (ushort_t)(r >> 16);
}
__device__ __forceinline__ float fast_tanh(float x) {
    float e = __expf(2.0f * x);
    return 1.0f - 2.0f * __builtin_amdgcn_rcpf(e + 1.0f);
}
__device__ __forceinline__ bf16x8 load_bfrag(const float* W, const float* M,
                                             size_t base) {
    float4 a = *(const float4*)(W + base);
    float4 b = *(const float4*)(W + base + 4);
    if (M) {
        float4 ma = *(const float4*)(M + base);
        float4 mb = *(const float4*)(M + base + 4);
        a.x *= ma.x; a.y *= ma.y; a.z *= ma.z; a.w *= ma.w;
        b.x *= mb.x; b.y *= mb.y; b.z *= mb.z; b.w *= mb.w;
    }
    union { bf16x8 v; ushort_t u[8]; } r;
    r.u[0] = f2bf(a.x); r.u[1] = f2bf(a.y); r.u[2] = f2bf(a.z); r.u[3] = f2bf(a.w);
    r.u[4] = f2bf(b.x); r.u[5] = f2bf(b.y); r.u[6] = f2bf(b.z); r.u[7] = f2bf(b.w);
    return r.v;
}

// Fragment-major LDS A-layout for hb (r9-verified): element (r,k) at
//   off = (k>>5)*512 + ((k>>3)&3)*128 + r*8 + (k&7)
// Reader lane L reads frag kk as b128 at element L*8 + kk*512 (linear,
// conflict-free). Pad-row lanes ((l15&2)!=0; C rows discarded) broadcast.
__device__ __forceinline__ int a_off(int r, int k) {
    return ((k >> 5) << 9) + (((k >> 3) & 3) << 7) + (r << 3) + (k & 7);
}

// ---------------------------------------------------------------------------
// scan_core<PUB,WAIT> (r17): the r12/r16-validated recurrence step, with the
// fuse projection REMOVED from the producer (r16 model: 64 MFMA/CU/step of
// issue was ~half the SIMD-serial work; r13 only MOVED the issue, r17
// removes it -> 8 dedicated fuser WGs do it as a batched GEMM off-path).
//  PUB : producer. h0 epilogue stores are agent-scope; every 8 steps:
//        vmcnt-draining __syncthreads + release flagsP (chunk count).
//        Waits proj0 window flags {8,24,32,32,32} before prefetching xp0.
//  WAIT: consumer. Spins flagsF (set by fuser) per 8-row xp1 chunk.
// Batch row i at A-slot (i>>1)*4+(i&1); C rows quad*4+reg (reg<2) ->
// lane(quad,l15) owns batches {quad*2,quad*2+1} x cols {wv*32+tc*16+l15}.
// ---------------------------------------------------------------------------
template<bool PUB, bool WAIT>
__device__ __forceinline__ void scan_core(
    int grp, ushort_t (*hb)[4096],
    const float* xp, int xp_stride, int xp_col,
    float* hout, int out_col,
    const float* Wrec, const float* Wmask, const float* tau_raw,
    unsigned int* flag, const unsigned int* projf)
{
    const int tid  = threadIdx.x;
    const int lane = tid & 63;
    const int wv   = tid >> 6;     // 0..7
    const int quad = lane >> 4;
    const int l15  = lane & 15;
    const int n0   = wv * 32;
    const int bg   = grp * 8;

    bf16x8 Bf[2][8];
    #pragma unroll
    for (int tc = 0; tc < 2; ++tc)
        #pragma unroll
        for (int kk = 0; kk < 8; ++kk)
            Bf[tc][kk] = load_bfrag(Wrec, Wmask,
                (size_t)(n0 + tc * 16 + l15) * H_ + kk * 32 + quad * 8);

    float inv_tau[2], h_prev[2][2];
    float xp_c[2][2], xp_n[2][2], xp_nn[2][2];
    #pragma unroll
    for (int tc = 0; tc < 2; ++tc) {
        inv_tau[tc] = 1.0f / (logf(1.0f + __expf(tau_raw[n0 + tc * 16 + l15])) + 0.1f);
        #pragma unroll
        for (int reg = 0; reg < 2; ++reg) {
            h_prev[tc][reg] = 0.0f;
            xp_c[tc][reg] = xp_n[tc][reg] = xp_nn[tc][reg] = 0.0f;
        }
    }

    int woff[2][2];
    #pragma unroll
    for (int tc = 0; tc < 2; ++tc)
        #pragma unroll
        for (int reg = 0; reg < 2; ++reg)
            woff[tc][reg] = a_off(quad * 4 + reg, n0 + tc * 16 + l15);
    const int ab = ((l15 & 2) == 0) ? (lane * 8) : 0;

    if (!WAIT) {   // prologue loads for t=0,1 (WAIT loads at chunk tops)
        if (PUB && projf != nullptr) {    // xp0 window 0 (rows 0..7) ready?
            if (tid < 8) {
                for (;;) {
                    unsigned v = __hip_atomic_load(&projf[bg + tid],
                                                   __ATOMIC_ACQUIRE,
                                                   __HIP_MEMORY_SCOPE_AGENT);
                    if (v == MAGIC) break;
                    __builtin_amdgcn_s_sleep(2);
                }
            }
            __syncthreads();
        }
        #pragma unroll
        for (int tc = 0; tc < 2; ++tc)
            #pragma unroll
            for (int reg = 0; reg < 2; ++reg) {
                const int b = bg + quad * 2 + reg;
                const int c = n0 + tc * 16 + l15;
                xp_c[tc][reg] = xp[(size_t)(b * T_ + 0) * xp_stride + xp_col + c];
                xp_n[tc][reg] = xp[(size_t)(b * T_ + 1) * xp_stride + xp_col + c];
            }
    }

    for (int i = tid; i < 4096; i += 512)
        ((unsigned int*)&hb[0][0])[i] = 0u;   // zero both buffers (16 KB)
    __syncthreads();

    for (int t = 0; t < T_; ++t) {
        const int rb = t & 1;

        #pragma unroll
        for (int tc = 0; tc < 2; ++tc)
            #pragma unroll
            for (int kk = 0; kk < 8; ++kk)
                PIN_FRAG(Bf[tc][kk]);

        if (WAIT && (t & 7) == 0) {
            if (tid == 0) {
                const unsigned need = (unsigned)(t >> 3) + 1u;
                for (;;) {
                    unsigned d = __hip_atomic_load(flag, __ATOMIC_ACQUIRE,
                                                   __HIP_MEMORY_SCOPE_AGENT) - MAGIC;
                    if (d >= need && d <= 16u) break;
                    __builtin_amdgcn_s_sleep(2);
                }
            }
            __syncthreads();
            #pragma unroll
            for (int tc = 0; tc < 2; ++tc)
                #pragma unroll
                for (int reg = 0; reg < 2; ++reg) {
                    const int b = bg + quad * 2 + reg;
                    xp_c[tc][reg] = xp[(size_t)(b * T_ + t) * xp_stride + xp_col
                                       + n0 + tc * 16 + l15];
                }
        }

        // A fragments (h(t-1)): linear conflict-free b128; pad lanes broadcast
        bf16x8 Af[8];
        {
            const ushort_t* a0 = &hb[rb][0];
            #pragma unroll
            for (int kk = 0; kk < 8; ++kk)
                Af[kk] = *(const bf16x8*)(a0 + ab + kk * 512);
        }

        // prefetch
        if (WAIT) {
            if ((t & 7) != 7 && t + 1 < T_) {
                #pragma unroll
                for (int tc = 0; tc < 2; ++tc)
                    #pragma unroll
                    for (int reg = 0; reg < 2; ++reg) {
                        const int b = bg + quad * 2 + reg;
                        xp_n[tc][reg] = xp[(size_t)(b * T_ + t + 1) * xp_stride
                                           + xp_col + n0 + tc * 16 + l15];
                    }
            }
        } else if (t + 2 < T_) {
            if (PUB && projf != nullptr) {
                // entering a new proj window? schedule {8,24,32,32,32}
                const int tp2 = t + 2;
                const int w = (tp2 == 8) ? 1 : (tp2 == 32) ? 2
                            : (tp2 == 64) ? 3 : (tp2 == 96) ? 4 : -1;
                if (w >= 0) {
                    if (tid < 8) {
                        for (;;) {
                            unsigned v = __hip_atomic_load(&projf[w * 64 + bg + tid],
                                                           __ATOMIC_ACQUIRE,
                                                           __HIP_MEMORY_SCOPE_AGENT);
                            if (v == MAGIC) break;
                            __builtin_amdgcn_s_sleep(2);
                        }
                    }
                    __syncthreads();
                }
            }
            #pragma unroll
            for (int tc = 0; tc < 2; ++tc)
                #pragma unroll
                for (int reg = 0; reg < 2; ++reg) {
                    const int b = bg + quad * 2 + reg;
                    xp_nn[tc][reg] = xp[(size_t)(b * T_ + t + 2) * xp_stride
                                        + xp_col + n0 + tc * 16 + l15];
                }
        }

        f32x4 acc[2] = {{0.f,0.f,0.f,0.f},{0.f,0.f,0.f,0.f}};
        #pragma unroll
        for (int kk = 0; kk < 8; ++kk)
            #pragma unroll
            for (int tc = 0; tc < 2; ++tc)
                acc[tc] = __builtin_amdgcn_mfma_f32_16x16x32_bf16(
                    Af[kk], Bf[tc][kk], acc[tc], 0, 0, 0);

        #pragma unroll
        for (int tc = 0; tc < 2; ++tc) {
            const int c = n0 + tc * 16 + l15;
            #pragma unroll
            for (int reg = 0; reg < 2; ++reg) {
                const int b = bg + quad * 2 + reg;
                const float pre = xp_c[tc][reg] + acc[tc][reg];
                const float hn  = h_prev[tc][reg]
                                + (fast_tanh(pre) - h_prev[tc][reg]) * inv_tau[tc];
                h_prev[tc][reg] = hn;
                hb[rb ^ 1][woff[tc][reg]] = f2bf(hn);
                if (PUB)   // agent-scope: cross-XCD visible once retired
                    __hip_atomic_store(&hout[(size_t)(b * T_ + t) * OW_ + out_col + c],
                                       hn, __ATOMIC_RELAXED, __HIP_MEMORY_SCOPE_AGENT);
                else
                    hout[(size_t)(b * T_ + t) * OW_ + out_col + c] = hn;
            }
        }
        if (WAIT) {
            if ((t & 7) != 7) {
                #pragma unroll
                for (int tc = 0; tc < 2; ++tc)
                    #pragma unroll
                    for (int reg = 0; reg < 2; ++reg)
                        xp_c[tc][reg] = xp_n[tc][reg];
            }
        } else {
            #pragma unroll
            for (int tc = 0; tc < 2; ++tc)
                #pragma unroll
                for (int reg = 0; reg < 2; ++reg) {
                    xp_c[tc][reg] = xp_n[tc][reg];
                    xp_n[tc][reg] = xp_nn[tc][reg];
                }
        }

        if (PUB && (t & 7) == 7) {
            __syncthreads();   // drains vmcnt -> h0 rows <= t retired
            if (tid == 0)
                __hip_atomic_store(flag, MAGIC + (unsigned)((t >> 3) + 1),
                                   __ATOMIC_RELEASE, __HIP_MEMORY_SCOPE_AGENT);
        } else if (t + 1 < T_) {
            LGKM_BARRIER();
        }
    }
}

// ---------------------------------------------------------------------------
// fuser_core (r17): one WG per batch group. Per 8-step chunk c: wait
// producer flagsP >= c, stage the 64 h0 rows (8 batches x 8 t) row-major,
// compute xp1 = h0 @ Wi1^T + b1 as a batched GEMM (512 MFMA / 8 waves, no
// pad rows, no serial chain), agent-store to xf, release flagsF = c.
// Values bit-identical to the old producer fuse (same f2bf(h0) @ bf16(Wi1)).
// ---------------------------------------------------------------------------
__device__ __forceinline__ void fuser_core(
    int grp, ushort_t (*As)[LP],
    const float* __restrict__ hsrc,          // out (h0 in cols 0..255)
    const float* __restrict__ Wi1, const float* __restrict__ b1v,
    float* __restrict__ xf,
    const unsigned int* flagP, unsigned int* flagF)
{
    const int tid  = threadIdx.x;
    const int lane = tid & 63;
    const int wv   = tid >> 6;
    const int quad = lane >> 4;
    const int l15  = lane & 15;
    const int n0   = wv * 32;
    const int bg   = grp * 8;

    bf16x8 Bf[2][8];
    float  bj[2];
    #pragma unroll
    for (int tc = 0; tc < 2; ++tc) {
        const int c = n0 + tc * 16 + l15;
        bj[tc] = b1v[c];
        #pragma unroll
        for (int kk = 0; kk < 8; ++kk)
            Bf[tc][kk] = load_bfrag(Wi1, nullptr,
                                    (size_t)c * H_ + kk * 32 + quad * 8);
    }

    const int srow = tid >> 3;        // 0..63: chunk row
    const int sseg = tid & 7;         // 32-col segment
    const int sb   = bg + (srow >> 3);

    for (int c = 1; c <= 16; ++c) {
        if (tid == 0) {
            for (;;) {
                unsigned d = __hip_atomic_load(flagP, __ATOMIC_ACQUIRE,
                                               __HIP_MEMORY_SCOPE_AGENT) - MAGIC;
                if (d >= (unsigned)c && d <= 16u) break;
                __builtin_amdgcn_s_sleep(2);
            }
        }
        __syncthreads();
        const int t0 = (c - 1) * 8;

        {   // stage 64 rows of h0 (f32 -> bf16), row-major [64][LP]
            const float* srcp = hsrc
                + (size_t)(sb * T_ + t0 + (srow & 7)) * OW_ + sseg * 32;
            union { uint4 q[4]; ushort_t u[32]; } pk;
            #pragma unroll
            for (int h = 0; h < 4; ++h) {
                float4 f0 = *(const float4*)(srcp + h * 8);
                float4 f1 = *(const float4*)(srcp + h * 8 + 4);
                pk.u[h*8+0] = f2bf(f0.x); pk.u[h*8+1] = f2bf(f0.y);
                pk.u[h*8+2] = f2bf(f0.z); pk.u[h*8+3] = f2bf(f0.w);
                pk.u[h*8+4] = f2bf(f1.x); pk.u[h*8+5] = f2bf(f1.y);
                pk.u[h*8+6] = f2bf(f1.z); pk.u[h*8+7] = f2bf(f1.w);
            }
            #pragma unroll
            for (int h = 0; h < 4; ++h)
                *(uint4*)&As[srow][sseg * 32 + h * 8] = pk.q[h];
        }
        __syncthreads();

        #pragma unroll
        for (int rt = 0; rt < 4; ++rt) {
            bf16x8 Af[8];
            #pragma unroll
            for (int kk = 0; kk < 8; ++kk)
                Af[kk] = *(const bf16x8*)&As[rt * 16 + l15][kk * 32 + quad * 8];

            f32x4 acc[2] = {{bj[0],bj[0],bj[0],bj[0]},
                            {bj[1],bj[1],bj[1],bj[1]}};
            #pragma unroll
            for (int kk = 0; kk < 8; ++kk)
                #pragma unroll
                for (int tc = 0; tc < 2; ++tc)
                    acc[tc] = __builtin_amdgcn_mfma_f32_16x16x32_bf16(
                        Af[kk], Bf[tc][kk], acc[tc], 0, 0, 0);

            #pragma unroll
            for (int tc = 0; tc < 2; ++tc) {
                const int cc = n0 + tc * 16 + l15;
                #pragma unroll
                for (int reg = 0; reg < 4; ++reg) {
                    const int r  = rt * 16 + quad * 4 + reg;
                    const int b  = bg + (r >> 3);
                    const int tt = t0 + (r & 7);
                    __hip_atomic_store(&xf[(size_t)(b * T_ + tt) * H_ + cc],
                                       acc[tc][reg],
                                       __ATOMIC_RELAXED, __HIP_MEMORY_SCOPE_AGENT);
                }
            }
        }
        __syncthreads();   // drains vmcnt (xf retired) + protects As reuse
        if (tid == 0)
            __hip_atomic_store(flagF, MAGIC + (unsigned)c,
                               __ATOMIC_RELEASE, __HIP_MEMORY_SCOPE_AGENT);
    }
}

// ---------------------------------------------------------------------------
// proj body: dst[r0+r][dst_col+n] = bias[n] + src[row(r)] @ Wi^T, nrows<=32.
// done != nullptr: agent-scope stores + per-block done flag (MAGIC, release).
// ---------------------------------------------------------------------------
__device__ __forceinline__ void proj_body(
    ushort_t (*As)[LP], int r0, int nrows,
    const float* __restrict__ src, int src_stride, int src_col,
    const int* __restrict__ tok,
    const float* __restrict__ Wi, const float* __restrict__ bias,
    float* __restrict__ dst, int dst_stride, int dst_col,
    unsigned int* done, int done_idx)
{
    const int tid  = threadIdx.x;
    const int lane = tid & 63;
    const int wv   = tid >> 6;
    const int quad = lane >> 4;
    const int l15  = lane & 15;
    const int n0   = wv * 32;

    bf16x8 Bf[2][8];
    float  bj[2];
    #pragma unroll
    for (int tc = 0; tc < 2; ++tc) {
        const int n = n0 + tc * 16 + l15;
        bj[tc] = bias[n];
        #pragma unroll
        for (int kk = 0; kk < 8; ++kk)
            Bf[tc][kk] = load_bfrag(Wi, nullptr, (size_t)n * H_ + kk * 32 + quad * 8);
    }

    {
        const int row = tid >> 4;
        const int seg = tid & 15;
        if (row < nrows) {
            const size_t sb = (tok ? (size_t)tok[r0 + row] : (size_t)(r0 + row))
                              * src_stride + src_col + seg * 16;
            union { uint4 q[2]; ushort_t u[16]; } p;
            #pragma unroll
            for (int h = 0; h < 2; ++h) {
                float4 f0 = *(const float4*)(src + sb + h * 8);
                float4 f1 = *(const float4*)(src + sb + h * 8 + 4);
                p.u[h*8+0] = f2bf(f0.x); p.u[h*8+1] = f2bf(f0.y);
                p.u[h*8+2] = f2bf(f0.z); p.u[h*8+3] = f2bf(f0.w);
                p.u[h*8+4] = f2bf(f1.x); p.u[h*8+5] = f2bf(f1.y);
                p.u[h*8+6] = f2bf(f1.z); p.u[h*8+7] = f2bf(f1.w);
            }
            *(uint4*)&As[row][seg * 16]     = p.q[0];
            *(uint4*)&As[row][seg * 16 + 8] = p.q[1];
        }
    }
    __syncthreads();

    #pragma unroll
    for (int rt = 0; rt < 2; ++rt) {
        if (rt * 16 >= nrows) break;   // garbage tiles skipped entirely
        bf16x8 Af[8];
        #pragma unroll
        for (int kk = 0; kk < 8; ++kk)
            Af[kk] = *(const bf16x8*)&As[rt * 16 + l15][kk * 32 + quad * 8];

        f32x4 acc[2] = {{bj[0],bj[0],bj[0],bj[0]}, {bj[1],bj[1],bj[1],bj[1]}};
        #pragma unroll
        for (int kk = 0; kk < 8; ++kk)
            #pragma unroll
            for (int tc = 0; tc < 2; ++tc)
                acc[tc] = __builtin_amdgcn_mfma_f32_16x16x32_bf16(
                    Af[kk], Bf[tc][kk], acc[tc], 0, 0, 0);

        #pragma unroll
        for (int tc = 0; tc < 2; ++tc) {
            const int c = n0 + tc * 16 + l15;
            #pragma unroll
            for (int reg = 0; reg < 4; ++reg) {
                const int rl = rt * 16 + quad * 4 + reg;
                if (rl < nrows) {
                    const int r = r0 + rl;
                    if (done)
                        __hip_atomic_store(&dst[(size_t)r * dst_stride + dst_col + c],
                                           acc[tc][reg],
                                           __ATOMIC_RELAXED, __HIP_MEMORY_SCOPE_AGENT);
                    else
                        dst[(size_t)r * dst_stride + dst_col + c] = acc[tc][reg];
                }
            }
        }
    }

    if (done) {
        __syncthreads();   // drains vmcnt -> all xp0 stores of this block retired
        if (tid == 0)
            __hip_atomic_store(&done[done_idx], MAGIC,
                               __ATOMIC_RELEASE, __HIP_MEMORY_SCOPE_AGENT);
    }
}

// ---------------------------------------------------------------------------
// Single dispatch, 4 roles: 0..7 producers (rec0, publishes h0 chunks),
// 8..15 consumers (rec1, waits fuser xp1 chunks), 16..23 fusers
// (xp1 = h0 @ Wi1^T + b1, batched per chunk), 24..343 proj0 blocks
// (windows {8,24,32,32,32} rows/batch; w=0 blocks first for a short
// producer prologue stall).
// ---------------------------------------------------------------------------
__global__ __launch_bounds__(512, 1)
void ltc_all(const int* __restrict__ tokens, const float* __restrict__ emb,
             const float* __restrict__ Wi0, const float* __restrict__ b0v,
             const float* __restrict__ Wr0, const float* __restrict__ m0,
             const float* __restrict__ t0v,
             const float* __restrict__ Wi1, const float* __restrict__ b1v,
             const float* __restrict__ Wr1, const float* __restrict__ m1,
             const float* __restrict__ t1v,
             float* out, float* xf,
             unsigned int* flagsP, unsigned int* flagsF, unsigned int* projf)
{
    __shared__ __align__(16) ushort_t smem[64][LP];   // 33792 B, role-shared
    if (blockIdx.x < 8)
        scan_core<true, false>(blockIdx.x, (ushort_t(*)[4096])&smem[0][0],
                               out, OW_, H_,     // xp0 in out cols 256..511
                               out, 0,           // h0 -> cols 0..255 (agent)
                               Wr0, m0, t0v, flagsP + blockIdx.x, projf);
    else if (blockIdx.x < 16)
        scan_core<false, true>(blockIdx.x - 8, (ushort_t(*)[4096])&smem[0][0],
                               xf, H_, 0,        // xp1 from workspace
                               out, H_,          // h1 -> cols 256..511
                               Wr1, m1, t1v, flagsF + (blockIdx.x - 8), nullptr);
    else if (blockIdx.x < 24)
        fuser_core(blockIdx.x - 16, smem, out, Wi1, b1v, xf,
                   flagsP + (blockIdx.x - 16), flagsF + (blockIdx.x - 16));
    else {
        const int p = blockIdx.x - 24;
        const int w = p >> 6, b = p & 63;
        const int r0 = b * T_ + (w == 0 ? 0 : (w == 1 ? 8 : 32 * (w - 1)));
        const int nr = (w == 0 ? 8 : (w == 1 ? 24 : 32));
        proj_body((ushort_t(*)[LP])smem, r0, nr, emb, E_, 0, tokens,
                  Wi0, b0v, out, OW_, H_, projf, p);
    }
}

// ---------------------------------------------------------------------------
// Fallback path (ws too small): sequential proj + standalone scans (proven).
// ---------------------------------------------------------------------------
__global__ __launch_bounds__(512, 1)
void ltc_single(const float* xp, int xp_stride, int xp_col,
                float* hout, int out_col,
                const float* __restrict__ Wr, const float* __restrict__ mk,
                const float* __restrict__ tu)
{
    __shared__ __align__(16) ushort_t hb[2][4096];
    scan_core<false, false>(blockIdx.x, hb, xp, xp_stride, xp_col,
                            hout, out_col, Wr, mk, tu, nullptr, nullptr);
}

__global__ __launch_bounds__(512, 2)
void proj_mfma(const float* __restrict__ src, int src_stride, int src_col,
               const int* __restrict__ tok,
               const float* __restrict__ Wi,
               const float* __restrict__ bias,
               float* __restrict__ dst, int dst_stride, int dst_col)
{
    __shared__ __align__(16) ushort_t As[32][LP];
    proj_body(As, blockIdx.x * 32, 32, src, src_stride, src_col, tok, Wi, bias,
              dst, dst_stride, dst_col, nullptr, 0);
}

extern "C" void kernel_launch(void* const* d_in, const int* in_sizes, int n_in,
                              void* d_out, int out_size, void* d_ws, size_t ws_size,
                              hipStream_t stream)
{
    const int*   tokens = (const int*)d_in[0];
    const float* emb    = (const float*)d_in[1];
    const float* W_in0  = (const float*)d_in[2];
    const float* W_rec0 = (const float*)d_in[3];
    const float* b0     = (const float*)d_in[4];
    const float* tau0   = (const float*)d_in[5];
    const float* mask0  = (const float*)d_in[6];
    const float* W_in1  = (const float*)d_in[7];
    const float* W_rec1 = (const float*)d_in[8];
    const float* b1     = (const float*)d_in[9];
    const float* tau1   = (const float*)d_in[10];
    const float* mask1  = (const float*)d_in[11];
    float* out = (float*)d_out;    // [8192, 512] f32
    (void)in_sizes; (void)n_in; (void)out_size;

    const size_t xf_bytes = (size_t)B_ * T_ * H_ * sizeof(float);
    // ws: [xf | flagsP (64B) | flagsF (64B) | projf (320*4B)]
    const size_t need = xf_bytes + 64 + 64 + 320 * sizeof(unsigned int);

    if (ws_size >= need) {
        // all flags arrive poisoned (0xAA..) each launch -> not-ready; the
        // window checks (==MAGIC / MAGIC+c in [1,16]) treat poison as unset.
        float* xf = (float*)d_ws;
        unsigned int* flagsP = (unsigned int*)((char*)d_ws + xf_bytes);
        unsigned int* flagsF = (unsigned int*)((char*)d_ws + xf_bytes + 64);
        unsigned int* projf  = (unsigned int*)((char*)d_ws + xf_bytes + 128);
        ltc_all<<<dim3(344), dim3(512), 0, stream>>>(
            tokens, emb, W_in0, b0, W_rec0, mask0, tau0,
            W_in1, b1, W_rec1, mask1, tau1, out, xf, flagsP, flagsF, projf);
    } else {
        proj_mfma<<<dim3(256), dim3(512), 0, stream>>>(
            emb, E_, 0, tokens, W_in0, b0, out, OW_, H_);
        ltc_single<<<dim3(8), dim3(512), 0, stream>>>(
            out, OW_, H_, out, 0, W_rec0, mask0, tau0);
        proj_mfma<<<dim3(256), dim3(512), 0, stream>>>(
            out, OW_, 0, nullptr, W_in1, b1, out, OW_, H_);
        ltc_single<<<dim3(8), dim3(512), 0, stream>>>(
            out, OW_, H_, out, H_, W_rec1, mask1, tau1);
    }
}